// Round 5
// baseline (123.116 us; speedup 1.0000x reference)
//
#include <hip/hip_runtime.h>

// B=4096, S=50, D=32, H=4, HD=8. One block = TWO batches, 512 threads.
// Waves 0-3 -> batch slot 0, waves 4-7 -> batch slot 1.
#define NB 4096
constexpr float kScale = 0.35355339059327378f; // 1/sqrt(8)
constexpr float NEGBIG = -3.0e38f;             // finite -inf (avoids inf-inf NaN)

typedef __attribute__((ext_vector_type(8))) short bf16x8;  // 8 bf16 = 4 VGPRs
typedef __attribute__((ext_vector_type(4))) float f32x4;

__device__ __forceinline__ unsigned short f2bf(float f) {   // RNE f32->bf16
  unsigned u = __float_as_uint(f);
  return (unsigned short)((u + 0x7FFFu + ((u >> 16) & 1u)) >> 16);
}
__device__ __forceinline__ float bf2f(unsigned short h) {
  return __uint_as_float(((unsigned)h) << 16);
}

__global__ __launch_bounds__(512) void mha(
    const float* __restrict__ Qg, const float* __restrict__ Kg,
    const float* __restrict__ Vg, const void* __restrict__ maskg,
    const float* __restrict__ WQg, const float* __restrict__ bQg,
    const float* __restrict__ WKg, const float* __restrict__ bKg,
    const float* __restrict__ WVg, const float* __restrict__ bVg,
    const float* __restrict__ WOg, const float* __restrict__ bOg,
    float* __restrict__ outg)
{
  __shared__ __align__(16) short sT0[2][2560];   // [64][40] bf16 act tile A, per batch
  __shared__ __align__(16) short sT1[2][2560];   // tile B
  __shared__ __align__(16) short sWt[5120];      // W^T bf16 [32][40]: WQ|WK|WV|WO
  __shared__ __align__(16) float sKV[2][3200];   // k2 [h][s][8] | v2 [h][s][8]
  __shared__ float sBias[128];                   // bQ|bK|bV|bO
  __shared__ unsigned sRaw[2][80];               // ballot-packed mask stream (2500 bits)
  __shared__ unsigned sMask[2][100];             // per-row words: [2i]=bits0-31,[2i+1]=bits32-49
  __shared__ unsigned sFlag;                     // 1 = byte mask, 0 = int32 mask
  // total ~58.3 KB -> 2 blocks/CU (16 waves)

  const int t = threadIdx.x;
  const int bb = blockIdx.x;          // 0..2047
  const int lane = t & 63;
  const int wv = t >> 6;              // 0..7
  const int wb = wv >> 2;             // wave's batch slot
  const int wt = wv & 3;              // wave's M-tile
  const int tb = t >> 8;              // thread's batch slot
  const int tl = t & 255;             // thread index within batch
  const int c = lane & 15, g = lane >> 4;
  const int b0 = bb * 2;

  auto stage_tile = [&](const float* __restrict__ src, short* dst) {
    #pragma unroll
    for (int it = 0; it < 2; ++it) {
      const int idx = tl + it*256;
      if (idx < 400) {
        const float4 x = ((const float4*)src)[idx];
        const int s = idx >> 3, qd = idx & 7;
        const unsigned lo = (unsigned)f2bf(x.x) | ((unsigned)f2bf(x.y) << 16);
        const unsigned hi = (unsigned)f2bf(x.z) | ((unsigned)f2bf(x.w) << 16);
        *(uint2*)&dst[s*40 + qd*4] = make_uint2(lo, hi);
      }
    }
  };

  // D = A(tile) @ W + bias ; bf16-tile or f32 head-layout output. Per-wave M-tile = wt.
  auto mfma_pass = [&](const short* At, const short* Bt, int biasOff,
                       short* dstTile, float* dstF32, float scale, bool toF32) {
    const bf16x8 a = *(const bf16x8*)&At[(wt*16 + c)*40 + g*8];
    #pragma unroll
    for (int Nj = 0; Nj < 2; ++Nj) {
      const bf16x8 bbf = *(const bf16x8*)&Bt[(Nj*16 + c)*40 + g*8];
      const float bvv = sBias[biasOff + Nj*16 + c];
      f32x4 acc = {bvv, bvv, bvv, bvv};
      acc = __builtin_amdgcn_mfma_f32_16x16x32_bf16(a, bbf, acc, 0, 0, 0);
      #pragma unroll
      for (int r = 0; r < 4; ++r) {
        const int row = wt*16 + g*4 + r;     // C/D: col=lane&15, row=(lane>>4)*4+reg
        const int col = Nj*16 + c;
        const float v = acc[r] * scale;
        if (toF32) {
          if (row < 50) dstF32[(col >> 3)*400 + row*8 + (col & 7)] = v;  // [h][s][hd]
        } else {
          dstTile[row*40 + col] = (short)f2bf(v);
        }
      }
    }
  };

  // ---- A: stage rawK; W^T bf16; biases; zero pad rows; mask-width flag ----
  stage_tile(Kg + (b0 + tb)*1600, sT0[tb]);
  {
    #pragma unroll
    for (int it = 0; it < 8; ++it) {
      const int idx = t + it*512;                 // 4096 weight elems
      const int m = idx >> 10, w = idx & 1023;
      const int k = w >> 5, d = w & 31;
      const float* Wp = (m == 0) ? WQg : (m == 1) ? WKg : (m == 2) ? WVg : WOg;
      sWt[m*1280 + d*40 + k] = (short)f2bf(Wp[w]);
    }
    if      (t < 32)  sBias[t] = bQg[t];
    else if (t < 64)  sBias[t] = bKg[t-32];
    else if (t < 96)  sBias[t] = bVg[t-64];
    else if (t < 128) sBias[t] = bOg[t-96];
    if (t >= 128 && t < 408) {                    // zero rows 50..63 of all 4 tiles
      const int z = t - 128, which = z / 70, o = z - which*70;
      short* dst = (which == 0) ? sT0[0] : (which == 1) ? sT1[0]
                 : (which == 2) ? sT0[1] : sT1[1];
      *(uint4*)&dst[2000 + o*8] = make_uint4(0,0,0,0);
    }
    if (t < 64) {                                 // int32 vs byte mask detection
      const unsigned w = ((const unsigned*)maskg)[t];
      const unsigned long long ball = __ballot(w > 1u);
      if (t == 0) sFlag = (ball != 0ull) ? 1u : 0u;
    }
  }
  __syncthreads();

  // ---- B: ballot-pack mask stream (10 chunks/wave); pass1 K ----
  {
    const unsigned flag = sFlag;
    const int mbase = (b0 + wb) * 2500;
    for (int ch = wt*10; ch < wt*10 + 10; ++ch) {
      const int idx = ch*64 + lane;
      unsigned val = 0;
      if (idx < 2500) {
        val = flag ? (unsigned)((const unsigned char*)maskg)[mbase + idx]
                   : (unsigned)((const unsigned*)maskg)[mbase + idx];
      }
      const unsigned long long m = __ballot(val != 0u);
      if (lane == 0) {
        sRaw[wb][ch*2]     = (unsigned)m;
        sRaw[wb][ch*2 + 1] = (unsigned)(m >> 32);
      }
    }
  }
  mfma_pass(sT0[wb], sWt + 1280, 32, sT1[wb], nullptr, 1.f, false);
  __syncthreads();

  // ---- C: extract per-row mask words; pass2 K -> k2 f32; stage rawV ----
  if (tl < 100) {
    const int i = tl >> 1, half = tl & 1;
    const int bitpos = 50*i + half*32;
    const int a = bitpos >> 5, sh = bitpos & 31;
    unsigned w = sRaw[tb][a] >> sh;
    if (sh) w |= sRaw[tb][a+1] << (32 - sh);
    sMask[tb][tl] = w;
  }
  mfma_pass(sT1[wb], sWt + 1280, 32, nullptr, sKV[wb], 1.f, true);
  stage_tile(Vg + (b0 + tb)*1600, sT0[tb]);
  __syncthreads();

  // ---- D: pass1 V ----
  mfma_pass(sT0[wb], sWt + 2560, 64, sT1[wb], nullptr, 1.f, false);
  __syncthreads();

  // ---- E: pass2 V -> v2 f32; stage rawQ ----
  mfma_pass(sT1[wb], sWt + 2560, 64, nullptr, sKV[wb] + 1600, 1.f, true);
  stage_tile(Qg + (b0 + tb)*1600, sT0[tb]);
  __syncthreads();

  // ---- F: pass1 Q ----
  mfma_pass(sT0[wb], sWt + 0, 0, sT1[wb], nullptr, 1.f, false);
  __syncthreads();

  // ---- G: pass2 Q (pre-scaled) -> q bf16 tile ----
  mfma_pass(sT1[wb], sWt + 0, 0, sT0[wb], nullptr, kScale, false);
  __syncthreads();

  // ---- H: attention, 1 query row per thread (tl<200); ctx -> sT1 ----
  if (tl < 200) {
    const int h = tl / 50, i = tl - h*50;
    float qr[8];
    {
      const bf16x8 qv = *(const bf16x8*)&sT0[tb][i*40 + h*8];
      #pragma unroll
      for (int e = 0; e < 8; ++e) qr[e] = bf2f((unsigned short)qv[e]);
    }
    const unsigned mw0 = sMask[tb][i*2], mw1 = sMask[tb][i*2 + 1];
    const float* kh = &sKV[tb][h*400];
    const float* vh = &sKV[tb][1600 + h*400];
    float sb[50];
    float mx = NEGBIG;
    #pragma unroll
    for (int j = 0; j < 50; ++j) {
      const float4 k0 = *(const float4*)&kh[j*8];
      const float4 k1 = *(const float4*)&kh[j*8 + 4];
      float s = qr[0]*k0.x;
      s = fmaf(qr[1],k0.y,s); s = fmaf(qr[2],k0.z,s); s = fmaf(qr[3],k0.w,s);
      s = fmaf(qr[4],k1.x,s); s = fmaf(qr[5],k1.y,s); s = fmaf(qr[6],k1.z,s); s = fmaf(qr[7],k1.w,s);
      const unsigned bit = (j < 32) ? ((mw0 >> j) & 1u) : ((mw1 >> (j-32)) & 1u);
      s = bit ? NEGBIG : s;
      sb[j] = s;
      mx = fmaxf(mx, s);
    }
    float sum = 0.f;
    float a0=0,a1=0,a2=0,a3=0,a4=0,a5=0,a6=0,a7=0;
    #pragma unroll
    for (int j = 0; j < 50; ++j) {
      const float p = __expf(sb[j] - mx);
      sum += p;
      const float4 v0 = *(const float4*)&vh[j*8];
      const float4 v1 = *(const float4*)&vh[j*8 + 4];
      a0 = fmaf(p,v0.x,a0); a1 = fmaf(p,v0.y,a1); a2 = fmaf(p,v0.z,a2); a3 = fmaf(p,v0.w,a3);
      a4 = fmaf(p,v1.x,a4); a5 = fmaf(p,v1.y,a5); a6 = fmaf(p,v1.z,a6); a7 = fmaf(p,v1.w,a7);
    }
    const float inv = 1.f / sum;
    const unsigned w0 = (unsigned)f2bf(a0*inv) | ((unsigned)f2bf(a1*inv) << 16);
    const unsigned w1 = (unsigned)f2bf(a2*inv) | ((unsigned)f2bf(a3*inv) << 16);
    const unsigned w2 = (unsigned)f2bf(a4*inv) | ((unsigned)f2bf(a5*inv) << 16);
    const unsigned w3 = (unsigned)f2bf(a6*inv) | ((unsigned)f2bf(a7*inv) << 16);
    *(uint4*)&sT1[tb][i*40 + h*8] = make_uint4(w0,w1,w2,w3);
  }
  __syncthreads();

  // ---- I: out = ctx @ WO + bO + Q (residual re-read, L1/L2-hot) ----
  {
    const bf16x8 a = *(const bf16x8*)&sT1[wb][(wt*16 + c)*40 + g*8];
    #pragma unroll
    for (int Nj = 0; Nj < 2; ++Nj) {
      const bf16x8 bbf = *(const bf16x8*)&sWt[3840 + (Nj*16 + c)*40 + g*8];
      const float bvv = sBias[96 + Nj*16 + c];
      f32x4 acc = {bvv, bvv, bvv, bvv};
      acc = __builtin_amdgcn_mfma_f32_16x16x32_bf16(a, bbf, acc, 0, 0, 0);
      #pragma unroll
      for (int r = 0; r < 4; ++r) {
        const int row = wt*16 + g*4 + r;
        const int col = Nj*16 + c;
        if (row < 50) {
          const int gi = (b0 + wb)*1600 + row*32 + col;
          outg[gi] = acc[r] + Qg[gi];
        }
      }
    }
  }
}

extern "C" void kernel_launch(void* const* d_in, const int* in_sizes, int n_in,
                              void* d_out, int out_size, void* d_ws, size_t ws_size,
                              hipStream_t stream) {
  const float* Q  = (const float*)d_in[0];
  const float* K  = (const float*)d_in[1];
  const float* V  = (const float*)d_in[2];
  const void*  M  = d_in[3];
  const float* WQ = (const float*)d_in[4];
  const float* bQ = (const float*)d_in[5];
  const float* WK = (const float*)d_in[6];
  const float* bK = (const float*)d_in[7];
  const float* WV = (const float*)d_in[8];
  const float* bV = (const float*)d_in[9];
  const float* WO = (const float*)d_in[10];
  const float* bO = (const float*)d_in[11];
  float* out = (float*)d_out;
  (void)d_ws; (void)ws_size; (void)in_sizes; (void)n_in; (void)out_size;

  hipLaunchKernelGGL(mha, dim3(NB/2), dim3(512), 0, stream,
                     Q, K, V, M, WQ, bQ, WK, bK, WV, bV, WO, bO, out);
}

// Round 6
// 79.695 us; speedup vs baseline: 1.5448x; 1.5448x over previous
//
#include <hip/hip_runtime.h>

// B=4096, S=50, D=32, H=4, HD=8. One block = one batch, 256 threads, wave = M-tile.
// 2 barriers total: all projection passes and the whole attention tail are
// wave-private (each wave reads/writes only its own 16 rows of every tile).
#define NB 4096
constexpr float kScale = 0.35355339059327378f; // 1/sqrt(8)

constexpr int ST = 40;   // bf16 tile stride ([64][40], rows 16B-aligned)
constexpr int SP = 72;   // P stride   ([64][72] bf16, rows 16B-aligned)
constexpr int SV = 72;   // V2t stride ([32][72] bf16: [d][j])

typedef __attribute__((ext_vector_type(8))) short bf16x8;
typedef __attribute__((ext_vector_type(4))) float f32x4;

__device__ __forceinline__ unsigned short f2bf(float f) {   // RNE f32->bf16
  unsigned u = __float_as_uint(f);
  return (unsigned short)((u + 0x7FFFu + ((u >> 16) & 1u)) >> 16);
}

__global__ __launch_bounds__(256) void mha(
    const float* __restrict__ Qg, const float* __restrict__ Kg,
    const float* __restrict__ Vg, const void* __restrict__ maskg,
    const float* __restrict__ WQg, const float* __restrict__ bQg,
    const float* __restrict__ WKg, const float* __restrict__ bKg,
    const float* __restrict__ WVg, const float* __restrict__ bVg,
    const float* __restrict__ WOg, const float* __restrict__ bOg,
    float* __restrict__ outg)
{
  __shared__ __align__(16) short sA[64*ST];      // rawK -> K2
  __shared__ __align__(16) short sB[64*ST];      // tmp  -> ctx
  __shared__ __align__(16) short sC[64*ST];      // rawV -> q (scaled)
  __shared__ __align__(16) short sV2[32*SV];     // V2 transposed [d][j], cols j>=50 zeroed
  __shared__ __align__(16) short sWt[4*32*ST];   // W^T bf16 [n=d][k]: WQ|WK|WV|WO
  __shared__ __align__(16) short sP[64*SP];      // rawQ (stride ST) early; P (stride SP) late
  __shared__ float sBias[128];                   // bQ|bK|bV|bO
  __shared__ unsigned sRaw[80];                  // ballot-packed mask stream (2560 bits)
  __shared__ unsigned sMask[100];                // per-row: [2i]=bits0-31, [2i+1]=bits32-49
  // ~40.7 KB -> 4 blocks/CU

  const int t = threadIdx.x;
  const int b = blockIdx.x;
  const int lane = t & 63;
  const int wv = t >> 6;              // wave id == M-tile index
  const int c = lane & 15, g = lane >> 4;

  auto stage_tile = [&](const float* __restrict__ src, short* dst) {
    #pragma unroll
    for (int it = 0; it < 2; ++it) {
      const int idx = t + it*256;
      if (idx < 400) {
        const float4 x = ((const float4*)src)[idx];
        const int s = idx >> 3, qd = idx & 7;
        const unsigned lo = (unsigned)f2bf(x.x) | ((unsigned)f2bf(x.y) << 16);
        const unsigned hi = (unsigned)f2bf(x.z) | ((unsigned)f2bf(x.w) << 16);
        *(uint2*)&dst[s*ST + qd*4] = make_uint2(lo, hi);
      }
    }
  };

  // dst = src @ W + b ; wave-private (A rows and C rows are the wave's own 16).
  auto projT = [&](const short* At, int wm, int biasOff, short* dstTile, float scale) {
    const bf16x8 a = *(const bf16x8*)&At[(wv*16 + c)*ST + g*8];
    #pragma unroll
    for (int Nj = 0; Nj < 2; ++Nj) {
      const bf16x8 bb = *(const bf16x8*)&sWt[wm*1280 + (Nj*16 + c)*ST + g*8];
      const float bv = sBias[biasOff + Nj*16 + c];
      f32x4 acc = {bv, bv, bv, bv};
      acc = __builtin_amdgcn_mfma_f32_16x16x32_bf16(a, bb, acc, 0, 0, 0);
      #pragma unroll
      for (int r = 0; r < 4; ++r) {
        const int row = wv*16 + g*4 + r;      // C/D: col=lane&15, row=(lane>>4)*4+reg
        dstTile[row*ST + Nj*16 + c] = (short)f2bf(acc[r] * scale);
      }
    }
  };
  // V2 pass writing transposed [d][j]; j>=50 zeroed so PV pad contributions are 0.
  auto projV2 = [&](const short* At, int wm, int biasOff) {
    const bf16x8 a = *(const bf16x8*)&At[(wv*16 + c)*ST + g*8];
    #pragma unroll
    for (int Nj = 0; Nj < 2; ++Nj) {
      const bf16x8 bb = *(const bf16x8*)&sWt[wm*1280 + (Nj*16 + c)*ST + g*8];
      const float bv = sBias[biasOff + Nj*16 + c];
      f32x4 acc = {bv, bv, bv, bv};
      acc = __builtin_amdgcn_mfma_f32_16x16x32_bf16(a, bb, acc, 0, 0, 0);
      #pragma unroll
      for (int r = 0; r < 4; ++r) {
        const int j = wv*16 + g*4 + r;        // row index = key j
        const int d = Nj*16 + c;
        sV2[d*SV + j] = (j < 50) ? (short)f2bf(acc[r]) : (short)0;
      }
    }
  };

  // ---- phase A: stage rawK/rawV/rawQ, W^T, biases; ballot-pack mask ----
  stage_tile(Kg + b*1600, sA);
  stage_tile(Vg + b*1600, sC);
  stage_tile(Qg + b*1600, (short*)sP);
  #pragma unroll
  for (int it = 0; it < 16; ++it) {
    const int idx = t + it*256;               // 4096 weight elems
    const int m = idx >> 10, w = idx & 1023;
    const int k = w >> 5, d = w & 31;
    const float* Wp = (m == 0) ? WQg : (m == 1) ? WKg : (m == 2) ? WVg : WOg;
    sWt[m*1280 + d*ST + k] = (short)f2bf(Wp[w]);
  }
  if      (t < 32)  sBias[t] = bQg[t];
  else if (t < 64)  sBias[t] = bKg[t-32];
  else if (t < 96)  sBias[t] = bVg[t-64];
  else if (t < 128) sBias[t] = bOg[t-96];
  {
    // per-wave mask-width detection (int32 0/1 words are always <=1)
    const unsigned w64 = ((const unsigned*)maskg)[lane];
    const bool byteMask = (__ballot(w64 > 1u) != 0ull);
    const int mbase = b * 2500;
    for (int ch = wv*10; ch < wv*10 + 10; ++ch) {
      const int idx = ch*64 + lane;
      unsigned val = 0;
      if (idx < 2500) {
        val = byteMask ? (unsigned)((const unsigned char*)maskg)[mbase + idx]
                       : (unsigned)((const unsigned*)maskg)[mbase + idx];
      }
      const unsigned long long m = __ballot(val != 0u);
      if (lane == 0) {
        sRaw[ch*2]     = (unsigned)m;
        sRaw[ch*2 + 1] = (unsigned)(m >> 32);
      }
    }
  }
  __syncthreads();

  // ---- phase B: mask extract + 6 chained projection passes (no internal barriers) ----
  if (t < 100) {
    const int i = t >> 1, half = t & 1;
    const int bitpos = 50*i + half*32;
    const int a = bitpos >> 5, sh = bitpos & 31;
    unsigned w = sRaw[a] >> sh;
    if (sh) w |= sRaw[a+1] << (32 - sh);
    sMask[t] = w;
  }
  projT(sA, 1, 32, sB, 1.f);          // pass1 K: rawK -> tmp
  projT(sB, 1, 32, sA, 1.f);          // pass2 K: tmp -> K2 (sA)
  projT(sC, 2, 64, sB, 1.f);          // pass1 V: rawV -> tmp
  projV2(sB, 2, 64);                  // pass2 V: tmp -> V2t
  projT((short*)sP, 0, 0, sB, 1.f);   // pass1 Q: rawQ -> tmp
  projT(sB, 0, 0, sC, kScale);        // pass2 Q: tmp -> q (sC, pre-scaled)
  __syncthreads();

  // ---- phase H: wave-private attention tail (no barriers) ----
  {
    const bf16x8 qf = *(const bf16x8*)&sC[(wv*16 + c)*ST + g*8];
    unsigned m0[4], m1[4];
    #pragma unroll
    for (int r = 0; r < 4; ++r) {
      const int row = wv*16 + g*4 + r;
      m0[r] = (row < 50) ? sMask[row*2]     : 0u;
      m1[r] = (row < 50) ? sMask[row*2 + 1] : 0u;
    }
    const bf16x8 zf = {0,0,0,0,0,0,0,0};

    #pragma unroll
    for (int h = 0; h < 4; ++h) {
      // QK^T for head h: A = q (full 32-wide rows), B = K2 with k-slices != head zeroed.
      f32x4 s[4];
      #pragma unroll
      for (int Nj = 0; Nj < 4; ++Nj) {
        const bf16x8 kf = *(const bf16x8*)&sA[(Nj*16 + c)*ST + g*8];
        const bf16x8 bb = (g == h) ? kf : zf;
        f32x4 z = {0.f, 0.f, 0.f, 0.f};
        s[Nj] = __builtin_amdgcn_mfma_f32_16x16x32_bf16(qf, bb, z, 0, 0, 0);
      }
      // softmax in C-regs (no max-sub: |s| tiny by construction); P -> LDS bf16
      float rinv[4];
      #pragma unroll
      for (int r = 0; r < 4; ++r) {
        const int row = wv*16 + g*4 + r;
        float rs = 0.f;
        #pragma unroll
        for (int Nj = 0; Nj < 4; ++Nj) {
          const int j = Nj*16 + c;
          const unsigned word = (Nj < 2) ? m0[r] : m1[r];
          const unsigned bit = (word >> (j & 31)) & 1u;
          const bool keep = (row < 50) && (j < 50) && (bit == 0u);
          const float p = keep ? __expf(s[Nj][r]) : 0.f;
          rs += p;
          sP[row*SP + j] = (short)f2bf(p);
        }
        rs += __shfl_xor(rs, 1);
        rs += __shfl_xor(rs, 2);
        rs += __shfl_xor(rs, 4);
        rs += __shfl_xor(rs, 8);
        rinv[r] = 1.f / rs;               // row->(g,r) mapping identical in PV C
      }
      // PV: A = P (own rows), B = V2t rows 8h..8h+8 (c&7 dup trick, write c<8 only)
      f32x4 cac = {0.f, 0.f, 0.f, 0.f};
      #pragma unroll
      for (int ks = 0; ks < 2; ++ks) {
        const bf16x8 pf = *(const bf16x8*)&sP[(wv*16 + c)*SP + ks*32 + g*8];
        const bf16x8 vf = *(const bf16x8*)&sV2[(h*8 + (c & 7))*SV + ks*32 + g*8];
        cac = __builtin_amdgcn_mfma_f32_16x16x32_bf16(pf, vf, cac, 0, 0, 0);
      }
      #pragma unroll
      for (int r = 0; r < 4; ++r) {
        const int row = wv*16 + g*4 + r;
        if (c < 8) sB[row*ST + h*8 + c] = (short)f2bf(cac[r] * rinv[r]);
      }
    }

    // WO + bias + residual + store (ctx rows are the wave's own)
    const bf16x8 af = *(const bf16x8*)&sB[(wv*16 + c)*ST + g*8];
    #pragma unroll
    for (int Nj = 0; Nj < 2; ++Nj) {
      const bf16x8 bb = *(const bf16x8*)&sWt[3840 + (Nj*16 + c)*ST + g*8];
      const float bv = sBias[96 + Nj*16 + c];
      f32x4 o = {bv, bv, bv, bv};
      o = __builtin_amdgcn_mfma_f32_16x16x32_bf16(af, bb, o, 0, 0, 0);
      #pragma unroll
      for (int r = 0; r < 4; ++r) {
        const int row = wv*16 + g*4 + r;
        const int col = Nj*16 + c;
        if (row < 50) {
          const int gi = b*1600 + row*32 + col;
          outg[gi] = o[r] + Qg[gi];
        }
      }
    }
  }
}

extern "C" void kernel_launch(void* const* d_in, const int* in_sizes, int n_in,
                              void* d_out, int out_size, void* d_ws, size_t ws_size,
                              hipStream_t stream) {
  const float* Q  = (const float*)d_in[0];
  const float* K  = (const float*)d_in[1];
  const float* V  = (const float*)d_in[2];
  const void*  M  = d_in[3];
  const float* WQ = (const float*)d_in[4];
  const float* bQ = (const float*)d_in[5];
  const float* WK = (const float*)d_in[6];
  const float* bK = (const float*)d_in[7];
  const float* WV = (const float*)d_in[8];
  const float* bV = (const float*)d_in[9];
  const float* WO = (const float*)d_in[10];
  const float* bO = (const float*)d_in[11];
  float* out = (float*)d_out;
  (void)d_ws; (void)ws_size; (void)in_sizes; (void)n_in; (void)out_size;

  hipLaunchKernelGGL(mha, dim3(NB), dim3(256), 0, stream,
                     Q, K, V, M, WQ, bQ, WK, bK, WV, bV, WO, bO, out);
}

// Round 7
// 68.921 us; speedup vs baseline: 1.7863x; 1.1563x over previous
//
#include <hip/hip_runtime.h>

// B=4096, S=50, D=32, H=4, HD=8. One block = one batch, 256 threads, wave = M-tile.
// 3 barriers. In-place MFMA projection chains (wave-private rows); P overlays dead K2+q.
#define NB 4096
constexpr float kScale = 0.35355339059327378f; // 1/sqrt(8)

constexpr int ST = 40;     // act/weight tile stride (shorts)
constexpr int SP = 72;     // P stride
constexpr int SV = 72;     // V2t stride
// regions in SH (shorts), all 16B-aligned:
constexpr int OFF_W  = 0;      // 5120: W^T bf16 [n=d][k]: WQ|WK|WV|WO
constexpr int OFF_A  = 5120;   // 2560: rawK -> K1 -> K2      (P base overlays A+C)
constexpr int OFF_C  = 7680;   // 2560: rawQ -> Q1 -> q
constexpr int OFF_B  = 10240;  // 2560: rawV -> V1(tmp) -> ctx
constexpr int OFF_V2 = 12800;  // 2376: V2t [33][72]: rows 0-31 = [d][j], row 32 = ones
constexpr int SH_LEN = 15176;  // 30,352 B (+bias/mask below) -> ~31.6 KB -> 5 blocks/CU

typedef __attribute__((ext_vector_type(8))) short bf16x8;
typedef __attribute__((ext_vector_type(4))) float f32x4;

__device__ __forceinline__ unsigned cvt2(float lo, float hi) {  // 2xf32 -> packed bf16 (RNE)
  unsigned u;
  asm("v_cvt_pk_bf16_f32 %0, %1, %2" : "=v"(u) : "v"(lo), "v"(hi));
  return u;
}
__device__ __forceinline__ short cvt1(float x) {
  return (short)(cvt2(x, x) & 0xFFFFu);
}

__global__ __launch_bounds__(256) void mha(
    const float* __restrict__ Qg, const float* __restrict__ Kg,
    const float* __restrict__ Vg, const void* __restrict__ maskg,
    const float* __restrict__ WQg, const float* __restrict__ bQg,
    const float* __restrict__ WKg, const float* __restrict__ bKg,
    const float* __restrict__ WVg, const float* __restrict__ bVg,
    const float* __restrict__ WOg, const float* __restrict__ bOg,
    float* __restrict__ outg)
{
  __shared__ __align__(16) short SH[SH_LEN];
  __shared__ float sBias[128];        // bQ|bK|bV|bO
  __shared__ unsigned sRaw[80];       // ballot-packed mask stream
  __shared__ unsigned sMask[100];     // per-row: [2i]=bits0-31, [2i+1]=bits32-49

  const int t = threadIdx.x;
  const int b = blockIdx.x;
  const int lane = t & 63;
  const int wv = t >> 6;              // wave id == M-tile
  const int c = lane & 15, g = lane >> 4;

  auto stage_tile = [&](const float* __restrict__ src, int dstOff) {
    #pragma unroll
    for (int it = 0; it < 2; ++it) {
      const int idx = t + it*256;
      if (idx < 400) {
        const float4 x = ((const float4*)src)[idx];
        const int s = idx >> 3, qd = idx & 7;
        *(uint2*)&SH[dstOff + s*ST + qd*4] = make_uint2(cvt2(x.x, x.y), cvt2(x.z, x.w));
      }
    }
  };

  // dst = src @ W + b (in-place safe: one A-frag ds_read per lane precedes all writes;
  // rows are wave-private)
  auto projT = [&](int srcOff, int wm, int biasOff, int dstOff, float scale) {
    const bf16x8 a = *(const bf16x8*)&SH[srcOff + (wv*16 + c)*ST + g*8];
    #pragma unroll
    for (int Nj = 0; Nj < 2; ++Nj) {
      const bf16x8 bb = *(const bf16x8*)&SH[OFF_W + wm*1280 + (Nj*16 + c)*ST + g*8];
      const float bv = sBias[biasOff + Nj*16 + c];
      f32x4 acc = {bv, bv, bv, bv};
      acc = __builtin_amdgcn_mfma_f32_16x16x32_bf16(a, bb, acc, 0, 0, 0);
      #pragma unroll
      for (int r = 0; r < 4; ++r)
        SH[dstOff + (wv*16 + g*4 + r)*ST + Nj*16 + c] = cvt1(acc[r] * scale);
    }
  };
  // pass2 of V, writing transposed [d][j]; j>=50 zeroed
  auto projV2 = [&](int srcOff, int wm, int biasOff) {
    const bf16x8 a = *(const bf16x8*)&SH[srcOff + (wv*16 + c)*ST + g*8];
    #pragma unroll
    for (int Nj = 0; Nj < 2; ++Nj) {
      const bf16x8 bb = *(const bf16x8*)&SH[OFF_W + wm*1280 + (Nj*16 + c)*ST + g*8];
      const float bv = sBias[biasOff + Nj*16 + c];
      f32x4 acc = {bv, bv, bv, bv};
      acc = __builtin_amdgcn_mfma_f32_16x16x32_bf16(a, bb, acc, 0, 0, 0);
      #pragma unroll
      for (int r = 0; r < 4; ++r) {
        const int j = wv*16 + g*4 + r;
        SH[OFF_V2 + (Nj*16 + c)*SV + j] = (j < 50) ? cvt1(acc[r]) : (short)0;
      }
    }
  };

  // ---- phase A: stage raw K/Q/V, weights (float4, transposed scatter), biases,
  //      V2t ones-row, ballot-packed mask ----
  stage_tile(Kg + b*1600, OFF_A);
  stage_tile(Qg + b*1600, OFF_C);
  stage_tile(Vg + b*1600, OFF_B);
  #pragma unroll
  for (int m = 0; m < 4; ++m) {
    const float* Wp = (m == 0) ? WQg : (m == 1) ? WKg : (m == 2) ? WVg : WOg;
    const float4 x = ((const float4*)Wp)[t];        // W[k][d0..d0+3]
    const int k = t >> 3, d0 = (t & 7)*4;
    const unsigned u0 = cvt2(x.x, x.y), u1 = cvt2(x.z, x.w);
    SH[OFF_W + m*1280 + (d0+0)*ST + k] = (short)(u0 & 0xFFFF);
    SH[OFF_W + m*1280 + (d0+1)*ST + k] = (short)(u0 >> 16);
    SH[OFF_W + m*1280 + (d0+2)*ST + k] = (short)(u1 & 0xFFFF);
    SH[OFF_W + m*1280 + (d0+3)*ST + k] = (short)(u1 >> 16);
  }
  if      (t < 32)  sBias[t] = bQg[t];
  else if (t < 64)  sBias[t] = bKg[t-32];
  else if (t < 96)  sBias[t] = bVg[t-64];
  else if (t < 128) sBias[t] = bOg[t-96];
  else if (t >= 128 && t < 164) ((unsigned*)&SH[OFF_V2 + 32*SV])[t-128] = 0x3F803F80u; // ones row
  {
    const unsigned w64 = ((const unsigned*)maskg)[lane];
    const bool byteMask = (__ballot(w64 > 1u) != 0ull);   // int32 0/1 words never exceed 1
    const int mbase = b * 2500;
    for (int ch = wv*10; ch < wv*10 + 10; ++ch) {
      const int idx = ch*64 + lane;
      unsigned val = 0;
      if (idx < 2500) {
        val = byteMask ? (unsigned)((const unsigned char*)maskg)[mbase + idx]
                       : (unsigned)((const unsigned*)maskg)[mbase + idx];
      }
      const unsigned long long m = __ballot(val != 0u);
      if (lane == 0) {
        sRaw[ch*2]     = (unsigned)m;
        sRaw[ch*2 + 1] = (unsigned)(m >> 32);
      }
    }
  }
  __syncthreads();

  // ---- phase B: mask extract + 6 in-place projection passes (wave-private) ----
  if (t < 100) {
    const int i = t >> 1, half = t & 1;
    const int bitpos = 50*i + half*32;
    const int a = bitpos >> 5, sh = bitpos & 31;
    unsigned w = sRaw[a] >> sh;
    if (sh) w |= sRaw[a+1] << (32 - sh);
    sMask[t] = w;
  }
  projT(OFF_A, 1, 32, OFF_A, 1.f);      // K pass1
  projT(OFF_A, 1, 32, OFF_A, 1.f);      // K pass2 -> K2
  projT(OFF_B, 2, 64, OFF_B, 1.f);      // V pass1
  projV2(OFF_B, 2, 64);                 // V pass2 -> V2t
  projT(OFF_C, 0, 0, OFF_C, 1.f);       // Q pass1
  projT(OFF_C, 0, 0, OFF_C, kScale);    // Q pass2 -> q (pre-scaled)
  __syncthreads();

  // ---- phase H: QK^T all heads up front; then barrier frees K2+q for P ----
  f32x4 s[4][4];
  {
    const bf16x8 qf = *(const bf16x8*)&SH[OFF_C + (wv*16 + c)*ST + g*8];
    bf16x8 kf[4];
    #pragma unroll
    for (int Nj = 0; Nj < 4; ++Nj)
      kf[Nj] = *(const bf16x8*)&SH[OFF_A + (Nj*16 + c)*ST + g*8];
    const bf16x8 zf = {0,0,0,0,0,0,0,0};
    #pragma unroll
    for (int h = 0; h < 4; ++h) {
      const bf16x8 ah = (g == h) ? qf : zf;   // zero non-head contraction slices
      #pragma unroll
      for (int Nj = 0; Nj < 4; ++Nj) {
        f32x4 z = {0.f, 0.f, 0.f, 0.f};
        s[h][Nj] = __builtin_amdgcn_mfma_f32_16x16x32_bf16(ah, kf[Nj], z, 0, 0, 0);
      }
    }
  }
  __syncthreads();   // all waves done reading K2/q -> P may overlay them

  bool keep[4][4];
  #pragma unroll
  for (int r = 0; r < 4; ++r) {
    const int row = wv*16 + g*4 + r;
    const unsigned m0 = (row < 50) ? sMask[row*2]     : 0xFFFFFFFFu;
    const unsigned m1 = (row < 50) ? sMask[row*2 + 1] : 0xFFFFFFFFu;
    #pragma unroll
    for (int Nj = 0; Nj < 4; ++Nj) {
      const int j = Nj*16 + c;
      const unsigned w = (Nj < 2) ? m0 : m1;
      keep[r][Nj] = (row < 50) && (j < 50) && (((w >> (j & 31)) & 1u) == 0u);
    }
  }

  short* SPp = &SH[OFF_A];    // P tile [64][SP], overlays dead K2+q
  #pragma unroll
  for (int h = 0; h < 4; ++h) {
    // softmax (no max-sub: scores are O(1) by construction); select kills pad/mask/inf
    #pragma unroll
    for (int r = 0; r < 4; ++r) {
      const int row = wv*16 + g*4 + r;
      #pragma unroll
      for (int Nj = 0; Nj < 4; ++Nj) {
        const float p = keep[r][Nj] ? __expf(s[h][Nj][r]) : 0.f;
        SPp[row*SP + Nj*16 + c] = cvt1(p);
      }
    }
    // PV: A = P rows (own), B = V2t rows h*8+c (c<8) / ones-row (c>=8 -> rowsum)
    f32x4 cac = {0.f, 0.f, 0.f, 0.f};
    const int vrow = (c < 8) ? (h*8 + c) : 32;
    #pragma unroll
    for (int ks = 0; ks < 2; ++ks) {
      const bf16x8 pf = *(const bf16x8*)&SPp[(wv*16 + c)*SP + ks*32 + g*8];
      const bf16x8 vf = *(const bf16x8*)&SH[OFF_V2 + vrow*SV + ks*32 + g*8];
      cac = __builtin_amdgcn_mfma_f32_16x16x32_bf16(pf, vf, cac, 0, 0, 0);
    }
    #pragma unroll
    for (int r = 0; r < 4; ++r) {
      const float rv = __shfl(__builtin_amdgcn_rcpf(cac[r]), (lane & 0x30) | 8, 64);
      if (c < 8)
        SH[OFF_B + (wv*16 + g*4 + r)*ST + h*8 + c] = cvt1(cac[r] * rv);
    }
  }

  // ---- epilogue: out = ctx @ WO + bO + Q (residual re-read, L2-hot) ----
  {
    const bf16x8 af = *(const bf16x8*)&SH[OFF_B + (wv*16 + c)*ST + g*8];
    #pragma unroll
    for (int Nj = 0; Nj < 2; ++Nj) {
      const bf16x8 bb = *(const bf16x8*)&SH[OFF_W + 3*1280 + (Nj*16 + c)*ST + g*8];
      const float bv = sBias[96 + Nj*16 + c];
      f32x4 o = {bv, bv, bv, bv};
      o = __builtin_amdgcn_mfma_f32_16x16x32_bf16(af, bb, o, 0, 0, 0);
      #pragma unroll
      for (int r = 0; r < 4; ++r) {
        const int row = wv*16 + g*4 + r;
        const int col = Nj*16 + c;
        if (row < 50) {
          const int gi = b*1600 + row*32 + col;
          outg[gi] = o[r] + Qg[gi];
        }
      }
    }
  }
}

extern "C" void kernel_launch(void* const* d_in, const int* in_sizes, int n_in,
                              void* d_out, int out_size, void* d_ws, size_t ws_size,
                              hipStream_t stream) {
  const float* Q  = (const float*)d_in[0];
  const float* K  = (const float*)d_in[1];
  const float* V  = (const float*)d_in[2];
  const void*  M  = d_in[3];
  const float* WQ = (const float*)d_in[4];
  const float* bQ = (const float*)d_in[5];
  const float* WK = (const float*)d_in[6];
  const float* bK = (const float*)d_in[7];
  const float* WV = (const float*)d_in[8];
  const float* bV = (const float*)d_in[9];
  const float* WO = (const float*)d_in[10];
  const float* bO = (const float*)d_in[11];
  float* out = (float*)d_out;
  (void)d_ws; (void)ws_size; (void)in_sizes; (void)n_in; (void)out_size;

  hipLaunchKernelGGL(mha, dim3(NB), dim3(256), 0, stream,
                     Q, K, V, M, WQ, bQ, WK, bK, WV, bV, WO, bO, out);
}

// Round 8
// 63.781 us; speedup vs baseline: 1.9303x; 1.0806x over previous
//
#include <hip/hip_runtime.h>

// B=4096, S=50, D=32, H=4, HD=8. One block = one batch, 256 threads, wave = 16-row tile.
// 3 barriers. All MFMA passes choose the orientation that makes the OUTPUT
// lane-contiguous (packed ds_write_b64), using that A-frag/B-frag both read
// "8 consecutive shorts from row (tile+c)" of a [major][k] buffer.
#define NB 4096
// fold 1/sqrt(8)*log2(e) into q: softmax then uses raw v_exp_f32 (=2^x)
constexpr float kQscale = 0.35355339059327378f * 1.4426950408889634f;

constexpr int ST = 40;     // [s][d] tile stride (shorts)
constexpr int SP = 72;     // P stride [q][key]
constexpr int SV = 72;     // V2t stride [d][j]
constexpr int OFF_W  = 0;      // 5120: W^T bf16 [d][k]: WQ|WK|WV|WO
constexpr int OFF_A  = 5120;   // 2560: rawK -> K1 -> K2 ; P overlays [OFF_A, OFF_A+4608)
constexpr int OFF_C  = 7680;   // 2560: rawQ -> Q1 -> q
constexpr int OFF_B  = 10240;  // 2560: rawV -> V1 -> ctx
constexpr int OFF_V2 = 12800;  // 2304: V2t [32][SV], cols j>=50 zeroed
constexpr int SH_LEN = 15104;  // 30,208 B (+ bias/mask) -> ~31.5 KB -> 5 blocks/CU

typedef __attribute__((ext_vector_type(8))) short bf16x8;
typedef __attribute__((ext_vector_type(4))) float f32x4;

__device__ __forceinline__ unsigned cvt2(float lo, float hi) {  // 2xf32 -> packed bf16 RNE
  unsigned u;
  asm("v_cvt_pk_bf16_f32 %0, %1, %2" : "=v"(u) : "v"(lo), "v"(hi));
  return u;
}
__device__ __forceinline__ float fexp2(float x) {               // 2^x, 1 inst
  float r;
  asm("v_exp_f32 %0, %1" : "=v"(r) : "v"(x));
  return r;
}

__global__ __launch_bounds__(256) void mha(
    const float* __restrict__ Qg, const float* __restrict__ Kg,
    const float* __restrict__ Vg, const void* __restrict__ maskg,
    const float* __restrict__ WQg, const float* __restrict__ bQg,
    const float* __restrict__ WKg, const float* __restrict__ bKg,
    const float* __restrict__ WVg, const float* __restrict__ bVg,
    const float* __restrict__ WOg, const float* __restrict__ bOg,
    float* __restrict__ outg)
{
  __shared__ __align__(16) short SH[SH_LEN];
  __shared__ __align__(16) float sBias[128];   // bQ|bK|bV|bO
  __shared__ unsigned sRaw[80];
  __shared__ unsigned sMask[128];              // per-row words (100 used)

  const int t = threadIdx.x;
  const int b = blockIdx.x;
  const int lane = t & 63;
  const int wv = t >> 6;
  const int c = lane & 15, g = lane >> 4;
  const int myrow = wv*16 + c;                 // the [s]-row this lane owns

  auto stage_tile = [&](const float* __restrict__ src, int dstOff) {
    #pragma unroll
    for (int it = 0; it < 2; ++it) {
      const int idx = t + it*256;
      if (idx < 400) {
        const float4 x = ((const float4*)src)[idx];
        const int s = idx >> 3, qd = idx & 7;
        *(uint2*)&SH[dstOff + s*ST + qd*4] = make_uint2(cvt2(x.x, x.y), cvt2(x.z, x.w));
      }
    }
  };

  // Y[s][:] = X[s][:] @ W + b via Y^T = W^T X^T : A = W^T rows, B = own X row,
  // D col = s (own row), D rows = d_out -> lane's 4 values are consecutive d => b64.
  auto projX = [&](int xOff, int wm, int biasOff, int yOff, float scale) {
    const bf16x8 xb = *(const bf16x8*)&SH[xOff + myrow*ST + g*8];
    #pragma unroll
    for (int Ni = 0; Ni < 2; ++Ni) {
      const bf16x8 wa = *(const bf16x8*)&SH[OFF_W + wm*1280 + (Ni*16 + c)*ST + g*8];
      const float4 bv = *(const float4*)&sBias[biasOff + Ni*16 + g*4];
      f32x4 acc = {bv.x, bv.y, bv.z, bv.w};
      acc = __builtin_amdgcn_mfma_f32_16x16x32_bf16(wa, xb, acc, 0, 0, 0);
      *(uint2*)&SH[yOff + myrow*ST + Ni*16 + g*4] =
          make_uint2(cvt2(acc[0]*scale, acc[1]*scale), cvt2(acc[2]*scale, acc[3]*scale));
    }
  };

  // ---- phase A: stage raw K/Q/V, W^T, biases, ballot-pack mask ----
  stage_tile(Kg + b*1600, OFF_A);
  stage_tile(Qg + b*1600, OFF_C);
  stage_tile(Vg + b*1600, OFF_B);
  #pragma unroll
  for (int m = 0; m < 4; ++m) {
    const float* Wp = (m == 0) ? WQg : (m == 1) ? WKg : (m == 2) ? WVg : WOg;
    const float4 x = ((const float4*)Wp)[t];         // W[k][d0..d0+3]
    const int k = t >> 3, d0 = (t & 7)*4;
    const unsigned u0 = cvt2(x.x, x.y), u1 = cvt2(x.z, x.w);
    SH[OFF_W + m*1280 + (d0+0)*ST + k] = (short)(u0 & 0xFFFF);
    SH[OFF_W + m*1280 + (d0+1)*ST + k] = (short)(u0 >> 16);
    SH[OFF_W + m*1280 + (d0+2)*ST + k] = (short)(u1 & 0xFFFF);
    SH[OFF_W + m*1280 + (d0+3)*ST + k] = (short)(u1 >> 16);
  }
  if      (t < 32)  sBias[t] = bQg[t];
  else if (t < 64)  sBias[t] = bKg[t-32];
  else if (t < 96)  sBias[t] = bVg[t-64];
  else if (t < 128) sBias[t] = bOg[t-96];
  {
    const unsigned w64 = ((const unsigned*)maskg)[lane];
    const bool byteMask = (__ballot(w64 > 1u) != 0ull);  // int32 0/1 words never exceed 1
    const int mbase = b * 2500;
    for (int ch = wv*10; ch < wv*10 + 10; ++ch) {
      const int idx = ch*64 + lane;
      unsigned val = 0;
      if (idx < 2500) {
        val = byteMask ? (unsigned)((const unsigned char*)maskg)[mbase + idx]
                       : (unsigned)((const unsigned*)maskg)[mbase + idx];
      }
      const unsigned long long m = __ballot(val != 0u);
      if (lane == 0) {
        sRaw[ch*2]     = (unsigned)m;
        sRaw[ch*2 + 1] = (unsigned)(m >> 32);
      }
    }
  }
  __syncthreads();

  // ---- phase B: mask extract + 6 projection passes (wave-private rows, in place) ----
  if (t < 100) {
    const int i = t >> 1, half = t & 1;
    const int bitpos = 50*i + half*32;
    const int a = bitpos >> 5, sh = bitpos & 31;
    unsigned w = sRaw[a] >> sh;
    if (sh) w |= sRaw[a+1] << (32 - sh);
    sMask[t] = w;
  }
  projX(OFF_A, 1, 32, OFF_A, 1.f);        // K pass1
  projX(OFF_A, 1, 32, OFF_A, 1.f);        // K pass2 -> K2
  projX(OFF_B, 2, 64, OFF_B, 1.f);        // V pass1
  {                                        // V pass2 -> V2t[d][j] (normal orientation:
    const bf16x8 a = *(const bf16x8*)&SH[OFF_B + myrow*ST + g*8];   // D rows = j -> packed)
    #pragma unroll
    for (int Nj = 0; Nj < 2; ++Nj) {
      const bf16x8 bb = *(const bf16x8*)&SH[OFF_W + 2*1280 + (Nj*16 + c)*ST + g*8];
      const float bv = sBias[64 + Nj*16 + c];
      f32x4 acc = {bv, bv, bv, bv};
      acc = __builtin_amdgcn_mfma_f32_16x16x32_bf16(a, bb, acc, 0, 0, 0);
      const int j0 = wv*16 + g*4;
      const float v0 = (j0+0 < 50) ? acc[0] : 0.f;
      const float v1 = (j0+1 < 50) ? acc[1] : 0.f;
      const float v2 = (j0+2 < 50) ? acc[2] : 0.f;
      const float v3 = (j0+3 < 50) ? acc[3] : 0.f;
      *(uint2*)&SH[OFF_V2 + (Nj*16 + c)*SV + j0] = make_uint2(cvt2(v0,v1), cvt2(v2,v3));
    }
  }
  projX(OFF_C, 0, 0, OFF_C, 1.f);         // Q pass1
  projX(OFF_C, 0, 0, OFF_C, kQscale);     // Q pass2 -> q (scale incl. log2e)
  __syncthreads();

  // ---- QK^T (transposed: D[key][q], lane owns query col = myrow) ----
  f32x4 s[4][4];                          // [h][Ni], key = Ni*16 + g*4 + r
  {
    const bf16x8 qb = *(const bf16x8*)&SH[OFF_C + myrow*ST + g*8];
    const bf16x8 zf = {0,0,0,0,0,0,0,0};
    #pragma unroll
    for (int Ni = 0; Ni < 4; ++Ni) {
      const bf16x8 kf = *(const bf16x8*)&SH[OFF_A + (Ni*16 + c)*ST + g*8];
      #pragma unroll
      for (int h = 0; h < 4; ++h) {
        const bf16x8 af = (g == h) ? kf : zf;   // feature slice g == head
        f32x4 z = {0.f, 0.f, 0.f, 0.f};
        s[h][Ni] = __builtin_amdgcn_mfma_f32_16x16x32_bf16(af, qb, z, 0, 0, 0);
      }
    }
  }
  __syncthreads();   // K2 + q dead -> P overlays them

  const unsigned m0 = (myrow < 50) ? sMask[myrow*2]     : 0xFFFFFFFFu;
  const unsigned m1 = (myrow < 50) ? sMask[myrow*2 + 1] : 0xFFFFFFFFu;
  bool keep[4][4];
  #pragma unroll
  for (int Ni = 0; Ni < 4; ++Ni) {
    const unsigned w = (Ni < 2) ? m0 : m1;
    #pragma unroll
    for (int r = 0; r < 4; ++r) {
      const int key = Ni*16 + g*4 + r;
      keep[Ni][r] = (key < 50) && (((w >> (key & 31)) & 1u) == 0u);
    }
  }

  short* SPp = &SH[OFF_A];                // P [64][SP] overlays dead K2+q
  #pragma unroll
  for (int h = 0; h < 4; ++h) {
    float ps[4][4];
    float rs = 0.f;
    #pragma unroll
    for (int Ni = 0; Ni < 4; ++Ni) {
      #pragma unroll
      for (int r = 0; r < 4; ++r) {
        const float e = fexp2(s[h][Ni][r]);
        const float p = keep[Ni][r] ? e : 0.f;   // select kills masked/pad/inf/NaN
        ps[Ni][r] = p;
        rs += p;
      }
    }
    rs += __shfl_xor(rs, 16);
    rs += __shfl_xor(rs, 32);
    const float ri = __builtin_amdgcn_rcpf(rs);
    #pragma unroll
    for (int Ni = 0; Ni < 4; ++Ni)              // raw exp; normalize at ctx write
      *(uint2*)&SPp[myrow*SP + Ni*16 + g*4] =
          make_uint2(cvt2(ps[Ni][0], ps[Ni][1]), cvt2(ps[Ni][2], ps[Ni][3]));
    // PV transposed: D[d'][q] = V_h^T . P^T ; same reads as normal, packed ctx write,
    // and rinv is already in the owning lane (q = myrow).
    f32x4 cac = {0.f, 0.f, 0.f, 0.f};
    #pragma unroll
    for (int ks = 0; ks < 2; ++ks) {
      const bf16x8 vf = *(const bf16x8*)&SH[OFF_V2 + (h*8 + (c & 7))*SV + ks*32 + g*8];
      const bf16x8 pf = *(const bf16x8*)&SPp[myrow*SP + ks*32 + g*8];
      cac = __builtin_amdgcn_mfma_f32_16x16x32_bf16(vf, pf, cac, 0, 0, 0);
    }
    if (g < 2)                                   // D rows 0..7 = valid head dims
      *(uint2*)&SH[OFF_B + myrow*ST + h*8 + g*4] =
          make_uint2(cvt2(cac[0]*ri, cac[1]*ri), cvt2(cac[2]*ri, cac[3]*ri));
  }

  // ---- epilogue: out = ctx @ WO + bO + Q (normal orientation, f32 to global) ----
  {
    const bf16x8 af = *(const bf16x8*)&SH[OFF_B + myrow*ST + g*8];
    #pragma unroll
    for (int Nj = 0; Nj < 2; ++Nj) {
      const bf16x8 bbf = *(const bf16x8*)&SH[OFF_W + 3*1280 + (Nj*16 + c)*ST + g*8];
      const float bv = sBias[96 + Nj*16 + c];
      f32x4 o = {bv, bv, bv, bv};
      o = __builtin_amdgcn_mfma_f32_16x16x32_bf16(af, bbf, o, 0, 0, 0);
      #pragma unroll
      for (int r = 0; r < 4; ++r) {
        const int row = wv*16 + g*4 + r;
        if (row < 50) {
          const int gi = b*1600 + row*32 + Nj*16 + c;
          outg[gi] = o[r] + Qg[gi];
        }
      }
    }
  }
}

extern "C" void kernel_launch(void* const* d_in, const int* in_sizes, int n_in,
                              void* d_out, int out_size, void* d_ws, size_t ws_size,
                              hipStream_t stream) {
  const float* Q  = (const float*)d_in[0];
  const float* K  = (const float*)d_in[1];
  const float* V  = (const float*)d_in[2];
  const void*  M  = d_in[3];
  const float* WQ = (const float*)d_in[4];
  const float* bQ = (const float*)d_in[5];
  const float* WK = (const float*)d_in[6];
  const float* bK = (const float*)d_in[7];
  const float* WV = (const float*)d_in[8];
  const float* bV = (const float*)d_in[9];
  const float* WO = (const float*)d_in[10];
  const float* bO = (const float*)d_in[11];
  float* out = (float*)d_out;
  (void)d_ws; (void)ws_size; (void)in_sizes; (void)n_in; (void)out_size;

  hipLaunchKernelGGL(mha, dim3(NB), dim3(256), 0, stream,
                     Q, K, V, M, WQ, bQ, WK, bK, WV, bV, WO, bO, out);
}

// Round 9
// 59.862 us; speedup vs baseline: 2.0567x; 1.0655x over previous
//
#include <hip/hip_runtime.h>

// B=4096, S=50, D=32, H=4, HD=8. One block = one batch, 256 threads, wave = 16-row tile.
// 3 barriers. Projection chains K/V/Q interleaved (2 RAW segments instead of 6);
// exp+pack fused per head; barrier 3 moved to just after the QK^T ds_reads.
#define NB 4096
// fold 1/sqrt(8)*log2(e) into q: softmax uses raw v_exp_f32 (=2^x)
constexpr float kQscale = 0.35355339059327378f * 1.4426950408889634f;

constexpr int ST = 40;     // [s][d] tile stride (shorts)
constexpr int SP = 72;     // P stride [q][key]
constexpr int SV = 72;     // V2t stride [d][j]
constexpr int OFF_W  = 0;      // 5120: W^T bf16 [d][k]: WQ|WK|WV|WO
constexpr int OFF_A  = 5120;   // 2560: rawK -> K1 -> K2 ; P overlays [OFF_A, OFF_A+4608)
constexpr int OFF_C  = 7680;   // 2560: rawQ -> Q1 -> q
constexpr int OFF_B  = 10240;  // 2560: rawV -> V1 -> ctx
constexpr int OFF_V2 = 12800;  // 2304: V2t [32][SV], cols j>=50 zeroed
constexpr int SH_LEN = 15104;  // ~31.5 KB total -> 5 blocks/CU at VGPR<=64

typedef __attribute__((ext_vector_type(8))) short bf16x8;
typedef __attribute__((ext_vector_type(4))) float f32x4;

__device__ __forceinline__ unsigned cvt2(float lo, float hi) {  // 2xf32 -> packed bf16 RNE
  unsigned u;
  asm("v_cvt_pk_bf16_f32 %0, %1, %2" : "=v"(u) : "v"(lo), "v"(hi));
  return u;
}
__device__ __forceinline__ float fexp2(float x) {               // 2^x, 1 inst
  float r;
  asm("v_exp_f32 %0, %1" : "=v"(r) : "v"(x));
  return r;
}

__global__ __launch_bounds__(256) void mha(
    const float* __restrict__ Qg, const float* __restrict__ Kg,
    const float* __restrict__ Vg, const void* __restrict__ maskg,
    const float* __restrict__ WQg, const float* __restrict__ bQg,
    const float* __restrict__ WKg, const float* __restrict__ bKg,
    const float* __restrict__ WVg, const float* __restrict__ bVg,
    const float* __restrict__ WOg, const float* __restrict__ bOg,
    float* __restrict__ outg)
{
  __shared__ __align__(16) short SH[SH_LEN];
  __shared__ __align__(16) float sBias[128];   // bQ|bK|bV|bO
  __shared__ unsigned sRaw[80];
  __shared__ unsigned sMask[128];              // per-row words (100 used)

  const int t = threadIdx.x;
  const int b = blockIdx.x;
  const int lane = t & 63;
  const int wv = t >> 6;
  const int c = lane & 15, g = lane >> 4;
  const int myrow = wv*16 + c;                 // the [s]-row this lane owns

  auto stage_tile = [&](const float* __restrict__ src, int dstOff) {
    #pragma unroll
    for (int it = 0; it < 2; ++it) {
      const int idx = t + it*256;
      if (idx < 400) {
        const float4 x = ((const float4*)src)[idx];
        const int s = idx >> 3, qd = idx & 7;
        *(uint2*)&SH[dstOff + s*ST + qd*4] = make_uint2(cvt2(x.x, x.y), cvt2(x.z, x.w));
      }
    }
  };

  // one projection level: Y^T = W^T X^T (+bias); D col = own row s, rows = d_out
  // -> lane's 4 outputs are consecutive d => packed b64 write. Wave-private rows.
  auto projStep = [&](bf16x8 xb, int wm, int biasOff, int yOff, float scale) {
    #pragma unroll
    for (int Ni = 0; Ni < 2; ++Ni) {
      const bf16x8 wa = *(const bf16x8*)&SH[OFF_W + wm*1280 + (Ni*16 + c)*ST + g*8];
      const float4 bv = *(const float4*)&sBias[biasOff + Ni*16 + g*4];
      f32x4 acc = {bv.x, bv.y, bv.z, bv.w};
      acc = __builtin_amdgcn_mfma_f32_16x16x32_bf16(wa, xb, acc, 0, 0, 0);
      *(uint2*)&SH[yOff + myrow*ST + Ni*16 + g*4] =
          make_uint2(cvt2(acc[0]*scale, acc[1]*scale), cvt2(acc[2]*scale, acc[3]*scale));
    }
  };

  // ---- phase A: stage raw K/Q/V, W^T, biases, ballot-pack mask ----
  stage_tile(Kg + b*1600, OFF_A);
  stage_tile(Qg + b*1600, OFF_C);
  stage_tile(Vg + b*1600, OFF_B);
  #pragma unroll
  for (int m = 0; m < 4; ++m) {
    const float* Wp = (m == 0) ? WQg : (m == 1) ? WKg : (m == 2) ? WVg : WOg;
    const float4 x = ((const float4*)Wp)[t];         // W[k][d0..d0+3]
    const int k = t >> 3, d0 = (t & 7)*4;
    const unsigned u0 = cvt2(x.x, x.y), u1 = cvt2(x.z, x.w);
    SH[OFF_W + m*1280 + (d0+0)*ST + k] = (short)(u0 & 0xFFFF);
    SH[OFF_W + m*1280 + (d0+1)*ST + k] = (short)(u0 >> 16);
    SH[OFF_W + m*1280 + (d0+2)*ST + k] = (short)(u1 & 0xFFFF);
    SH[OFF_W + m*1280 + (d0+3)*ST + k] = (short)(u1 >> 16);
  }
  if      (t < 32)  sBias[t] = bQg[t];
  else if (t < 64)  sBias[t] = bKg[t-32];
  else if (t < 96)  sBias[t] = bVg[t-64];
  else if (t < 128) sBias[t] = bOg[t-96];
  {
    const unsigned w64 = ((const unsigned*)maskg)[lane];
    const bool byteMask = (__ballot(w64 > 1u) != 0ull);  // int32 0/1 words never exceed 1
    const int mbase = b * 2500;
    #pragma unroll
    for (int cc = 0; cc < 10; ++cc) {                    // unrolled: 10 loads issue together
      const int ch = wv*10 + cc;
      const int idx = ch*64 + lane;
      unsigned val = 0;
      if (idx < 2500) {
        val = byteMask ? (unsigned)((const unsigned char*)maskg)[mbase + idx]
                       : (unsigned)((const unsigned*)maskg)[mbase + idx];
      }
      const unsigned long long m = __ballot(val != 0u);
      if (lane == 0) {
        sRaw[ch*2]     = (unsigned)m;
        sRaw[ch*2 + 1] = (unsigned)(m >> 32);
      }
    }
  }
  __syncthreads();

  // ---- phase B: mask extract + interleaved projection levels ----
  if (t < 100) {
    const int i = t >> 1, half = t & 1;
    const int bitpos = 50*i + half*32;
    const int a = bitpos >> 5, sh = bitpos & 31;
    unsigned w = sRaw[a] >> sh;
    if (sh) w |= sRaw[a+1] << (32 - sh);
    sMask[t] = w;
  }
  {  // level 1: three independent chains, reads grouped up front
    const bf16x8 aK = *(const bf16x8*)&SH[OFF_A + myrow*ST + g*8];
    const bf16x8 aV = *(const bf16x8*)&SH[OFF_B + myrow*ST + g*8];
    const bf16x8 aQ = *(const bf16x8*)&SH[OFF_C + myrow*ST + g*8];
    projStep(aK, 1, 32, OFF_A, 1.f);
    projStep(aV, 2, 64, OFF_B, 1.f);
    projStep(aQ, 0, 0,  OFF_C, 1.f);
  }
  {  // level 2
    const bf16x8 aK = *(const bf16x8*)&SH[OFF_A + myrow*ST + g*8];
    const bf16x8 aV = *(const bf16x8*)&SH[OFF_B + myrow*ST + g*8];
    const bf16x8 aQ = *(const bf16x8*)&SH[OFF_C + myrow*ST + g*8];
    projStep(aK, 1, 32, OFF_A, 1.f);      // -> K2
    {  // V pass2 -> V2t[d][j] (normal orientation: D rows = d, cols = own j)
      #pragma unroll
      for (int Nj = 0; Nj < 2; ++Nj) {
        const bf16x8 bb = *(const bf16x8*)&SH[OFF_W + 2*1280 + (Nj*16 + c)*ST + g*8];
        const float bv = sBias[64 + Nj*16 + c];
        f32x4 acc = {bv, bv, bv, bv};
        acc = __builtin_amdgcn_mfma_f32_16x16x32_bf16(aV, bb, acc, 0, 0, 0);
        const int j0 = wv*16 + g*4;
        const float v0 = (j0+0 < 50) ? acc[0] : 0.f;
        const float v1 = (j0+1 < 50) ? acc[1] : 0.f;
        const float v2 = (j0+2 < 50) ? acc[2] : 0.f;
        const float v3 = (j0+3 < 50) ? acc[3] : 0.f;
        *(uint2*)&SH[OFF_V2 + (Nj*16 + c)*SV + j0] = make_uint2(cvt2(v0,v1), cvt2(v2,v3));
      }
    }
    projStep(aQ, 0, 0, OFF_C, kQscale);   // -> q (scale incl. log2e)
  }
  __syncthreads();   // barrier 2: K2 / q / V2t all visible

  // ---- QK^T reads (registers), then EARLY barrier 3 frees K2+q for P overlay ----
  const bf16x8 qb = *(const bf16x8*)&SH[OFF_C + myrow*ST + g*8];
  bf16x8 kf[4];
  #pragma unroll
  for (int Ni = 0; Ni < 4; ++Ni)
    kf[Ni] = *(const bf16x8*)&SH[OFF_A + (Ni*16 + c)*ST + g*8];
  const unsigned m0 = (myrow < 50) ? sMask[myrow*2]     : 0xFFFFFFFFu;
  const unsigned m1 = (myrow < 50) ? sMask[myrow*2 + 1] : 0xFFFFFFFFu;
  __syncthreads();   // all waves' reads done; register-only work crosses freely

  short* SPp = &SH[OFF_A];                // P [64][SP] overlays dead K2+q
  const bf16x8 zf = {0,0,0,0,0,0,0,0};
  #pragma unroll
  for (int h = 0; h < 4; ++h) {
    // V2t frags first (independent of P)
    const bf16x8 vf0 = *(const bf16x8*)&SH[OFF_V2 + (h*8 + (c & 7))*SV + g*8];
    const bf16x8 vf1 = *(const bf16x8*)&SH[OFF_V2 + (h*8 + (c & 7))*SV + 32 + g*8];
    // QK^T for head h (zero non-head k-slices of q; regs only)
    const bf16x8 qh = (g == h) ? qb : zf;
    f32x4 s[4];
    #pragma unroll
    for (int Ni = 0; Ni < 4; ++Ni) {
      f32x4 z = {0.f, 0.f, 0.f, 0.f};
      s[Ni] = __builtin_amdgcn_mfma_f32_16x16x32_bf16(kf[Ni], qh, z, 0, 0, 0);
    }
    // exp + pack (select kills masked/pad/inf/NaN); row-sum across g-groups
    float rs = 0.f;
    unsigned pk[8];
    #pragma unroll
    for (int Ni = 0; Ni < 4; ++Ni) {
      const unsigned w = (Ni < 2) ? m0 : m1;
      float p[4];
      #pragma unroll
      for (int r = 0; r < 4; ++r) {
        const int key = Ni*16 + g*4 + r;
        const bool keep = (key < 50) && (((w >> (key & 31)) & 1u) == 0u);
        const float e = fexp2(s[Ni][r]);
        p[r] = keep ? e : 0.f;
        rs += p[r];
      }
      pk[Ni*2]   = cvt2(p[0], p[1]);
      pk[Ni*2+1] = cvt2(p[2], p[3]);
    }
    rs += __shfl_xor(rs, 16);
    rs += __shfl_xor(rs, 32);
    const float ri = __builtin_amdgcn_rcpf(rs);
    // P -> LDS (raw exp; normalize at ctx write)
    #pragma unroll
    for (int Ni = 0; Ni < 4; ++Ni)
      *(uint2*)&SPp[myrow*SP + Ni*16 + g*4] = make_uint2(pk[Ni*2], pk[Ni*2+1]);
    // PV transposed: D[d'][q]; rinv already in the owning lane (q = myrow)
    const bf16x8 pf0 = *(const bf16x8*)&SPp[myrow*SP + g*8];
    const bf16x8 pf1 = *(const bf16x8*)&SPp[myrow*SP + 32 + g*8];
    f32x4 cac = {0.f, 0.f, 0.f, 0.f};
    cac = __builtin_amdgcn_mfma_f32_16x16x32_bf16(vf0, pf0, cac, 0, 0, 0);
    cac = __builtin_amdgcn_mfma_f32_16x16x32_bf16(vf1, pf1, cac, 0, 0, 0);
    if (g < 2)                                   // D rows 0..7 = valid head dims
      *(uint2*)&SH[OFF_B + myrow*ST + h*8 + g*4] =
          make_uint2(cvt2(cac[0]*ri, cac[1]*ri), cvt2(cac[2]*ri, cac[3]*ri));
  }

  // ---- epilogue: out = ctx @ WO + bO + Q (ctx rows wave-private; no barrier) ----
  {
    const bf16x8 af = *(const bf16x8*)&SH[OFF_B + myrow*ST + g*8];
    #pragma unroll
    for (int Nj = 0; Nj < 2; ++Nj) {
      const bf16x8 bbf = *(const bf16x8*)&SH[OFF_W + 3*1280 + (Nj*16 + c)*ST + g*8];
      const float bv = sBias[96 + Nj*16 + c];
      f32x4 o = {bv, bv, bv, bv};
      o = __builtin_amdgcn_mfma_f32_16x16x32_bf16(af, bbf, o, 0, 0, 0);
      #pragma unroll
      for (int r = 0; r < 4; ++r) {
        const int row = wv*16 + g*4 + r;
        if (row < 50) {
          const int gi = b*1600 + row*32 + Nj*16 + c;
          outg[gi] = o[r] + Qg[gi];
        }
      }
    }
  }
}

extern "C" void kernel_launch(void* const* d_in, const int* in_sizes, int n_in,
                              void* d_out, int out_size, void* d_ws, size_t ws_size,
                              hipStream_t stream) {
  const float* Q  = (const float*)d_in[0];
  const float* K  = (const float*)d_in[1];
  const float* V  = (const float*)d_in[2];
  const void*  M  = d_in[3];
  const float* WQ = (const float*)d_in[4];
  const float* bQ = (const float*)d_in[5];
  const float* WK = (const float*)d_in[6];
  const float* bK = (const float*)d_in[7];
  const float* WV = (const float*)d_in[8];
  const float* bV = (const float*)d_in[9];
  const float* WO = (const float*)d_in[10];
  const float* bO = (const float*)d_in[11];
  float* out = (float*)d_out;
  (void)d_ws; (void)ws_size; (void)in_sizes; (void)n_in; (void)out_size;

  hipLaunchKernelGGL(mha, dim3(NB), dim3(256), 0, stream,
                     Q, K, V, M, WQ, bQ, WK, bK, WV, bV, WO, bO, out);
}

// Round 10
// 57.740 us; speedup vs baseline: 2.1323x; 1.0368x over previous
//
#include <hip/hip_runtime.h>

// B=4096, S=50, D=32, H=4, HD=8. One block = one batch, 256 threads, wave = 16-row tile.
// 3 barriers. V2t overlays dead WQ+WK (LDS 26.9KB -> 6 blocks/CU). Head loop is
// software-pipelined: QK^T+exp of head h+1 fills the P write->read RAW gap of head h.
#define NB 4096
// fold 1/sqrt(8)*log2(e) into q: softmax uses raw v_exp_f32 (=2^x)
constexpr float kQscale = 0.35355339059327378f * 1.4426950408889634f;

constexpr int ST = 40;     // [s][d] tile stride (shorts)
constexpr int SP = 72;     // P stride [q][key]
constexpr int SV = 72;     // V2t stride [d][j]
constexpr int OFF_W  = 0;      // 5120: W^T bf16 [d][k]: WQ|WK|WV|WO
constexpr int OFF_V2 = 0;      // 2304: V2t [32][SV] overlays WQ+WK after barrier 2
constexpr int OFF_A  = 5120;   // 2560: rawK -> K1 -> K2 ; P overlays [OFF_A, OFF_A+4608)
constexpr int OFF_C  = 7680;   // 2560: rawQ -> Q1 -> q
constexpr int OFF_B  = 10240;  // 2560: rawV -> V1 -> ctx
constexpr int SH_LEN = 12800;  // 25,600 B (+aux ~1.3KB) -> ~26.9 KB -> 6 blocks/CU

typedef __attribute__((ext_vector_type(8))) short bf16x8;
typedef __attribute__((ext_vector_type(4))) float f32x4;

__device__ __forceinline__ unsigned cvt2(float lo, float hi) {  // 2xf32 -> packed bf16 RNE
  unsigned u;
  asm("v_cvt_pk_bf16_f32 %0, %1, %2" : "=v"(u) : "v"(lo), "v"(hi));
  return u;
}
__device__ __forceinline__ float fexp2(float x) {               // 2^x, 1 inst
  float r;
  asm("v_exp_f32 %0, %1" : "=v"(r) : "v"(x));
  return r;
}

__global__ __launch_bounds__(256) void mha(
    const float* __restrict__ Qg, const float* __restrict__ Kg,
    const float* __restrict__ Vg, const void* __restrict__ maskg,
    const float* __restrict__ WQg, const float* __restrict__ bQg,
    const float* __restrict__ WKg, const float* __restrict__ bKg,
    const float* __restrict__ WVg, const float* __restrict__ bVg,
    const float* __restrict__ WOg, const float* __restrict__ bOg,
    float* __restrict__ outg)
{
  __shared__ __align__(16) short SH[SH_LEN];
  __shared__ __align__(16) float sBias[128];   // bQ|bK|bV|bO
  __shared__ unsigned sRaw[80];
  __shared__ unsigned sMask[128];              // per-row words (100 used)

  const int t = threadIdx.x;
  const int b = blockIdx.x;
  const int lane = t & 63;
  const int wv = t >> 6;
  const int c = lane & 15, g = lane >> 4;
  const int myrow = wv*16 + c;                 // the [s]-row this lane owns

  auto stage_tile = [&](const float* __restrict__ src, int dstOff) {
    #pragma unroll
    for (int it = 0; it < 2; ++it) {
      const int idx = t + it*256;
      if (idx < 400) {
        const float4 x = ((const float4*)src)[idx];
        const int s = idx >> 3, qd = idx & 7;
        *(uint2*)&SH[dstOff + s*ST + qd*4] = make_uint2(cvt2(x.x, x.y), cvt2(x.z, x.w));
      }
    }
  };

  // Y^T = W^T X^T (+bias); lane's 4 outputs are consecutive d => packed b64 write.
  auto projStep = [&](bf16x8 xb, int wm, int biasOff, int yOff, float scale) {
    #pragma unroll
    for (int Ni = 0; Ni < 2; ++Ni) {
      const bf16x8 wa = *(const bf16x8*)&SH[OFF_W + wm*1280 + (Ni*16 + c)*ST + g*8];
      const float4 bv = *(const float4*)&sBias[biasOff + Ni*16 + g*4];
      f32x4 acc = {bv.x, bv.y, bv.z, bv.w};
      acc = __builtin_amdgcn_mfma_f32_16x16x32_bf16(wa, xb, acc, 0, 0, 0);
      *(uint2*)&SH[yOff + myrow*ST + Ni*16 + g*4] =
          make_uint2(cvt2(acc[0]*scale, acc[1]*scale), cvt2(acc[2]*scale, acc[3]*scale));
    }
  };

  // ---- phase A: stage raw K/Q/V, W^T, biases; speculative-byte mask + ballot pack ----
  // detection load + speculative byte loads issue in parallel (bytes always in-bounds)
  const unsigned w64det = ((const unsigned*)maskg)[lane];
  unsigned valB[10];
  #pragma unroll
  for (int cc = 0; cc < 10; ++cc) {
    const int idx = (wv*10 + cc)*64 + lane;
    valB[cc] = (idx < 2500) ? (unsigned)((const unsigned char*)maskg)[b*2500 + idx] : 0u;
  }
  stage_tile(Kg + b*1600, OFF_A);
  stage_tile(Qg + b*1600, OFF_C);
  stage_tile(Vg + b*1600, OFF_B);
  #pragma unroll
  for (int m = 0; m < 4; ++m) {
    const float* Wp = (m == 0) ? WQg : (m == 1) ? WKg : (m == 2) ? WVg : WOg;
    const float4 x = ((const float4*)Wp)[t];         // W[k][d0..d0+3]
    const int k = t >> 3, d0 = (t & 7)*4;
    const unsigned u0 = cvt2(x.x, x.y), u1 = cvt2(x.z, x.w);
    SH[OFF_W + m*1280 + (d0+0)*ST + k] = (short)(u0 & 0xFFFF);
    SH[OFF_W + m*1280 + (d0+1)*ST + k] = (short)(u0 >> 16);
    SH[OFF_W + m*1280 + (d0+2)*ST + k] = (short)(u1 & 0xFFFF);
    SH[OFF_W + m*1280 + (d0+3)*ST + k] = (short)(u1 >> 16);
  }
  if      (t < 32)  sBias[t] = bQg[t];
  else if (t < 64)  sBias[t] = bKg[t-32];
  else if (t < 96)  sBias[t] = bVg[t-64];
  else if (t < 128) sBias[t] = bOg[t-96];
  {
    const bool byteMask = (__ballot(w64det > 1u) != 0ull);  // int32 0/1 words never >1
    #pragma unroll
    for (int cc = 0; cc < 10; ++cc) {
      const int ch = wv*10 + cc;
      const int idx = ch*64 + lane;
      unsigned val;
      if (byteMask) val = valB[cc];                          // fast path, already loaded
      else          val = (idx < 2500) ? ((const unsigned*)maskg)[b*2500 + idx] : 0u;
      const unsigned long long m = __ballot(val != 0u);
      if (lane == 0) {
        sRaw[ch*2]     = (unsigned)m;
        sRaw[ch*2 + 1] = (unsigned)(m >> 32);
      }
    }
  }
  __syncthreads();   // barrier 1

  // ---- phase B: mask extract + interleaved projections; V2 result held in regs ----
  if (t < 100) {
    const int i = t >> 1, half = t & 1;
    const int bitpos = 50*i + half*32;
    const int a = bitpos >> 5, sh = bitpos & 31;
    unsigned w = sRaw[a] >> sh;
    if (sh) w |= sRaw[a+1] << (32 - sh);
    sMask[t] = w;
  }
  {  // level 1: three independent chains, reads grouped up front
    const bf16x8 aK = *(const bf16x8*)&SH[OFF_A + myrow*ST + g*8];
    const bf16x8 aV = *(const bf16x8*)&SH[OFF_B + myrow*ST + g*8];
    const bf16x8 aQ = *(const bf16x8*)&SH[OFF_C + myrow*ST + g*8];
    projStep(aK, 1, 32, OFF_A, 1.f);
    projStep(aV, 2, 64, OFF_B, 1.f);
    projStep(aQ, 0, 0,  OFF_C, 1.f);
  }
  f32x4 vacc0, vacc1;   // V pass2 result, written to LDS only after barrier 2
  {  // level 2
    const bf16x8 aK = *(const bf16x8*)&SH[OFF_A + myrow*ST + g*8];
    const bf16x8 aV = *(const bf16x8*)&SH[OFF_B + myrow*ST + g*8];
    const bf16x8 aQ = *(const bf16x8*)&SH[OFF_C + myrow*ST + g*8];
    projStep(aK, 1, 32, OFF_A, 1.f);      // -> K2
    projStep(aQ, 0, 0, OFF_C, kQscale);   // -> q (scale incl. log2e)
    {
      const bf16x8 b0 = *(const bf16x8*)&SH[OFF_W + 2*1280 + c*ST + g*8];
      const bf16x8 b1 = *(const bf16x8*)&SH[OFF_W + 2*1280 + (16 + c)*ST + g*8];
      const float bv0 = sBias[64 + c], bv1 = sBias[64 + 16 + c];
      f32x4 z0 = {bv0, bv0, bv0, bv0}, z1 = {bv1, bv1, bv1, bv1};
      vacc0 = __builtin_amdgcn_mfma_f32_16x16x32_bf16(aV, b0, z0, 0, 0, 0);
      vacc1 = __builtin_amdgcn_mfma_f32_16x16x32_bf16(aV, b1, z1, 0, 0, 0);
    }
  }
  __syncthreads();   // barrier 2: K2/q visible; all W-QK reads drained

  // ---- between barriers: V2t -> dead WQ+WK region; QK^T reads + head-0 compute ----
  {
    const int j0 = wv*16 + g*4;
    const float v0 = (j0+0 < 50) ? vacc0[0] : 0.f;
    const float v1 = (j0+1 < 50) ? vacc0[1] : 0.f;
    const float v2 = (j0+2 < 50) ? vacc0[2] : 0.f;
    const float v3 = (j0+3 < 50) ? vacc0[3] : 0.f;
    *(uint2*)&SH[OFF_V2 + c*SV + j0] = make_uint2(cvt2(v0,v1), cvt2(v2,v3));
    const float u0 = (j0+0 < 50) ? vacc1[0] : 0.f;
    const float u1 = (j0+1 < 50) ? vacc1[1] : 0.f;
    const float u2 = (j0+2 < 50) ? vacc1[2] : 0.f;
    const float u3 = (j0+3 < 50) ? vacc1[3] : 0.f;
    *(uint2*)&SH[OFF_V2 + (16 + c)*SV + j0] = make_uint2(cvt2(u0,u1), cvt2(u2,u3));
  }
  const bf16x8 qb = *(const bf16x8*)&SH[OFF_C + myrow*ST + g*8];
  bf16x8 kf[4];
  #pragma unroll
  for (int Ni = 0; Ni < 4; ++Ni)
    kf[Ni] = *(const bf16x8*)&SH[OFF_A + (Ni*16 + c)*ST + g*8];
  const unsigned m0 = (myrow < 50) ? sMask[myrow*2]     : 0xFFFFFFFFu;
  const unsigned m1 = (myrow < 50) ? sMask[myrow*2 + 1] : 0xFFFFFFFFu;
  const bf16x8 zf = {0,0,0,0,0,0,0,0};

  // QK^T + exp for one head; registers only (safe to compute across barriers)
  auto qkt_exp = [&](int h, unsigned pk[8], float& ri) {
    const bf16x8 qh = (g == h) ? qb : zf;
    float rs = 0.f;
    #pragma unroll
    for (int Ni = 0; Ni < 4; ++Ni) {
      f32x4 z = {0.f, 0.f, 0.f, 0.f};
      const f32x4 s = __builtin_amdgcn_mfma_f32_16x16x32_bf16(kf[Ni], qh, z, 0, 0, 0);
      const unsigned w = (Ni < 2) ? m0 : m1;
      float p[4];
      #pragma unroll
      for (int r = 0; r < 4; ++r) {
        const int key = Ni*16 + g*4 + r;
        const bool keep = (key < 50) && (((w >> (key & 31)) & 1u) == 0u);
        p[r] = keep ? fexp2(s[r]) : 0.f;     // select kills masked/pad/inf/NaN
        rs += p[r];
      }
      pk[Ni*2]   = cvt2(p[0], p[1]);
      pk[Ni*2+1] = cvt2(p[2], p[3]);
    }
    rs += __shfl_xor(rs, 16);
    rs += __shfl_xor(rs, 32);
    ri = __builtin_amdgcn_rcpf(rs);
  };

  unsigned pkA[8]; float riA;
  qkt_exp(0, pkA, riA);
  __syncthreads();   // barrier 3: V2t visible; K2/q dead -> P overlays them

  short* SPp = &SH[OFF_A];                // P [64][SP]
  #pragma unroll
  for (int h = 0; h < 4; ++h) {
    #pragma unroll
    for (int Ni = 0; Ni < 4; ++Ni)        // P(h) -> LDS (raw exp; normalize at ctx)
      *(uint2*)&SPp[myrow*SP + Ni*16 + g*4] = make_uint2(pkA[Ni*2], pkA[Ni*2+1]);
    const bf16x8 vf0 = *(const bf16x8*)&SH[OFF_V2 + (h*8 + (c & 7))*SV + g*8];
    const bf16x8 vf1 = *(const bf16x8*)&SH[OFF_V2 + (h*8 + (c & 7))*SV + 32 + g*8];
    unsigned pkN[8] = {0,0,0,0,0,0,0,0}; float riN = 0.f;
    if (h < 3) qkt_exp(h+1, pkN, riN);    // fills the P write->read RAW gap
    const bf16x8 pf0 = *(const bf16x8*)&SPp[myrow*SP + g*8];
    const bf16x8 pf1 = *(const bf16x8*)&SPp[myrow*SP + 32 + g*8];
    f32x4 cac = {0.f, 0.f, 0.f, 0.f};
    cac = __builtin_amdgcn_mfma_f32_16x16x32_bf16(vf0, pf0, cac, 0, 0, 0);
    cac = __builtin_amdgcn_mfma_f32_16x16x32_bf16(vf1, pf1, cac, 0, 0, 0);
    if (g < 2)                            // D rows 0..7 = valid head dims
      *(uint2*)&SH[OFF_B + myrow*ST + h*8 + g*4] =
          make_uint2(cvt2(cac[0]*riA, cac[1]*riA), cvt2(cac[2]*riA, cac[3]*riA));
    #pragma unroll
    for (int e = 0; e < 8; ++e) pkA[e] = pkN[e];
    riA = riN;
  }

  // ---- epilogue: out = ctx @ WO + bO + Q (residual loads hoisted before ctx read) ----
  {
    float res[2][4];
    #pragma unroll
    for (int Nj = 0; Nj < 2; ++Nj)
      #pragma unroll
      for (int r = 0; r < 4; ++r) {
        const int row = wv*16 + g*4 + r;
        res[Nj][r] = (row < 50) ? Qg[b*1600 + row*32 + Nj*16 + c] : 0.f;
      }
    const bf16x8 af = *(const bf16x8*)&SH[OFF_B + myrow*ST + g*8];
    #pragma unroll
    for (int Nj = 0; Nj < 2; ++Nj) {
      const bf16x8 bbf = *(const bf16x8*)&SH[OFF_W + 3*1280 + (Nj*16 + c)*ST + g*8];
      const float bv = sBias[96 + Nj*16 + c];
      f32x4 o = {bv, bv, bv, bv};
      o = __builtin_amdgcn_mfma_f32_16x16x32_bf16(af, bbf, o, 0, 0, 0);
      #pragma unroll
      for (int r = 0; r < 4; ++r) {
        const int row = wv*16 + g*4 + r;
        if (row < 50)
          outg[b*1600 + row*32 + Nj*16 + c] = o[r] + res[Nj][r];
      }
    }
  }
}

extern "C" void kernel_launch(void* const* d_in, const int* in_sizes, int n_in,
                              void* d_out, int out_size, void* d_ws, size_t ws_size,
                              hipStream_t stream) {
  const float* Q  = (const float*)d_in[0];
  const float* K  = (const float*)d_in[1];
  const float* V  = (const float*)d_in[2];
  const void*  M  = d_in[3];
  const float* WQ = (const float*)d_in[4];
  const float* bQ = (const float*)d_in[5];
  const float* WK = (const float*)d_in[6];
  const float* bK = (const float*)d_in[7];
  const float* WV = (const float*)d_in[8];
  const float* bV = (const float*)d_in[9];
  const float* WO = (const float*)d_in[10];
  const float* bO = (const float*)d_in[11];
  float* out = (float*)d_out;
  (void)d_ws; (void)ws_size; (void)in_sizes; (void)n_in; (void)out_size;

  hipLaunchKernelGGL(mha, dim3(NB), dim3(256), 0, stream,
                     Q, K, V, M, WQ, bQ, WK, bK, WV, bV, WO, bO, out);
}

// Round 12
// 56.458 us; speedup vs baseline: 2.1807x; 1.0227x over previous
//
#include <hip/hip_runtime.h>

// B=4096, S=50, D=32, H=4, HD=8. One block = one batch, 256 threads, wave = 16-row tile.
// 3 barriers. P and ctx never touch LDS: cross-g-group exchange done with
// v_permlane16/32_swap_b32 (dst = FIRST operand; semantics verified by derivation:
// xchF(a,b): a=[a0,a2,b0,b2], b=[a1,a3,b1,b3] by 16-lane groups).
#define NB 4096
// fold 1/sqrt(8)*log2(e) into q: softmax uses raw v_exp_f32 (=2^x)
constexpr float kQscale = 0.35355339059327378f * 1.4426950408889634f;

constexpr int ST = 40;     // [s][d] tile stride (shorts)
constexpr int SV = 72;     // V2t stride [d][j]
constexpr int OFF_W  = 0;      // 5120: W^T bf16 [d][k]: WQ|WK|WV|WO
constexpr int OFF_V2 = 0;      // 2304: V2t [32][SV] overlays dead WQ+WK after barrier 2
constexpr int OFF_A  = 5120;   // 2560: rawK -> K1 -> K2
constexpr int OFF_C  = 7680;   // 2560: rawQ -> Q1 -> q
constexpr int OFF_B  = 10240;  // 2560: rawV -> V1
constexpr int SH_LEN = 12800;  // 25,600 B (+bias 512 + raw 320) ≈ 26.4 KB -> 6 blocks/CU

typedef __attribute__((ext_vector_type(8))) short bf16x8;
typedef __attribute__((ext_vector_type(4))) float f32x4;
typedef __attribute__((ext_vector_type(4))) unsigned u32x4;

__device__ __forceinline__ unsigned cvt2(float lo, float hi) {  // 2xf32 -> packed bf16 RNE
  unsigned u;
  asm("v_cvt_pk_bf16_f32 %0, %1, %2" : "=v"(u) : "v"(lo), "v"(hi));
  return u;
}
__device__ __forceinline__ float fexp2(float x) {               // 2^x, 1 inst
  float r;
  asm("v_exp_f32 %0, %1" : "=v"(r) : "v"(x));
  return r;
}
// xchF(a,b): P32(dst=a,src=b) then P16(dst=a,src=b).
// P32: dst groups{2,3} <-> src groups{0,1}; P16: dst odd groups <-> src even groups.
// Net (by 16-lane groups): a = [a0,a2,b0,b2], b = [a1,a3,b1,b3].
__device__ __forceinline__ void xchF(unsigned& a, unsigned& b) {
  asm volatile("v_permlane32_swap_b32 %0, %1" : "+v"(a), "+v"(b));
  asm volatile("v_permlane16_swap_b32 %0, %1" : "+v"(a), "+v"(b));
}

__global__ __launch_bounds__(256) void mha(
    const float* __restrict__ Qg, const float* __restrict__ Kg,
    const float* __restrict__ Vg, const void* __restrict__ maskg,
    const float* __restrict__ WQg, const float* __restrict__ bQg,
    const float* __restrict__ WKg, const float* __restrict__ bKg,
    const float* __restrict__ WVg, const float* __restrict__ bVg,
    const float* __restrict__ WOg, const float* __restrict__ bOg,
    float* __restrict__ outg)
{
  __shared__ __align__(16) short SH[SH_LEN];
  __shared__ __align__(16) float sBias[128];   // bQ|bK|bV|bO
  __shared__ unsigned sRaw[80];                // ballot-packed mask bits (2500)

  const int t = threadIdx.x;
  const int b = blockIdx.x;
  const int lane = t & 63;
  const int wv = t >> 6;
  const int c = lane & 15, g = lane >> 4;
  const int myrow = wv*16 + c;                 // the [s]-row / q-row this lane owns

  auto stage_tile = [&](const float* __restrict__ src, int dstOff) {
    #pragma unroll
    for (int it = 0; it < 2; ++it) {
      const int idx = t + it*256;
      if (idx < 400) {
        const float4 x = ((const float4*)src)[idx];
        const int s = idx >> 3, qd = idx & 7;
        *(uint2*)&SH[dstOff + s*ST + qd*4] = make_uint2(cvt2(x.x, x.y), cvt2(x.z, x.w));
      }
    }
  };

  // Y^T = W^T X^T (+bias); lane's 4 outputs are consecutive d => packed b64 write.
  auto projStep = [&](bf16x8 xb, int wm, int biasOff, int yOff, float scale) {
    #pragma unroll
    for (int Ni = 0; Ni < 2; ++Ni) {
      const bf16x8 wa = *(const bf16x8*)&SH[OFF_W + wm*1280 + (Ni*16 + c)*ST + g*8];
      const float4 bv = *(const float4*)&sBias[biasOff + Ni*16 + g*4];
      f32x4 acc = {bv.x, bv.y, bv.z, bv.w};
      acc = __builtin_amdgcn_mfma_f32_16x16x32_bf16(wa, xb, acc, 0, 0, 0);
      *(uint2*)&SH[yOff + myrow*ST + Ni*16 + g*4] =
          make_uint2(cvt2(acc[0]*scale, acc[1]*scale), cvt2(acc[2]*scale, acc[3]*scale));
    }
  };

  // ---- phase A: stage raw K/Q/V + W^T + biases; speculative-byte mask + ballot pack ----
  const unsigned w64det = ((const unsigned*)maskg)[lane];
  unsigned valB[10];
  #pragma unroll
  for (int cc = 0; cc < 10; ++cc) {
    const int idx = (wv*10 + cc)*64 + lane;
    valB[cc] = (idx < 2500) ? (unsigned)((const unsigned char*)maskg)[b*2500 + idx] : 0u;
  }
  stage_tile(Kg + b*1600, OFF_A);
  stage_tile(Qg + b*1600, OFF_C);
  stage_tile(Vg + b*1600, OFF_B);
  {
    // W^T staging with packed LDS writes: read W[k0..k0+3][d] (coalesced dwords),
    // write W^T[d][k0..k0+3] as one b64.
    const int wd = t & 31, wk0 = (t >> 5) * 4;
    #pragma unroll
    for (int m = 0; m < 4; ++m) {
      const float* Wp = (m == 0) ? WQg : (m == 1) ? WKg : (m == 2) ? WVg : WOg;
      const float w0 = Wp[(wk0+0)*32 + wd];
      const float w1 = Wp[(wk0+1)*32 + wd];
      const float w2 = Wp[(wk0+2)*32 + wd];
      const float w3 = Wp[(wk0+3)*32 + wd];
      *(uint2*)&SH[OFF_W + m*1280 + wd*ST + wk0] = make_uint2(cvt2(w0,w1), cvt2(w2,w3));
    }
  }
  if      (t < 32)  sBias[t] = bQg[t];
  else if (t < 64)  sBias[t] = bKg[t-32];
  else if (t < 96)  sBias[t] = bVg[t-64];
  else if (t < 128) sBias[t] = bOg[t-96];
  {
    const bool byteMask = (__ballot(w64det > 1u) != 0ull);  // int32 0/1 words never >1
    #pragma unroll
    for (int cc = 0; cc < 10; ++cc) {
      const int ch = wv*10 + cc;
      const int idx = ch*64 + lane;
      unsigned val;
      if (byteMask) val = valB[cc];
      else          val = (idx < 2500) ? ((const unsigned*)maskg)[b*2500 + idx] : 0u;
      const unsigned long long m = __ballot(val != 0u);
      if (lane == 0) {
        sRaw[ch*2]     = (unsigned)m;
        sRaw[ch*2 + 1] = (unsigned)(m >> 32);
      }
    }
  }
  __syncthreads();   // barrier 1

  // ---- phase B: two interleaved projection levels (wave-private rows, in place) ----
  {
    const bf16x8 aK = *(const bf16x8*)&SH[OFF_A + myrow*ST + g*8];
    const bf16x8 aV = *(const bf16x8*)&SH[OFF_B + myrow*ST + g*8];
    const bf16x8 aQ = *(const bf16x8*)&SH[OFF_C + myrow*ST + g*8];
    projStep(aK, 1, 32, OFF_A, 1.f);
    projStep(aV, 2, 64, OFF_B, 1.f);
    projStep(aQ, 0, 0,  OFF_C, 1.f);
  }
  f32x4 vacc0, vacc1;   // V pass2 result, LDS write deferred past barrier 2
  {
    const bf16x8 aK = *(const bf16x8*)&SH[OFF_A + myrow*ST + g*8];
    const bf16x8 aV = *(const bf16x8*)&SH[OFF_B + myrow*ST + g*8];
    const bf16x8 aQ = *(const bf16x8*)&SH[OFF_C + myrow*ST + g*8];
    projStep(aK, 1, 32, OFF_A, 1.f);      // -> K2
    projStep(aQ, 0, 0, OFF_C, kQscale);   // -> q (scale incl. log2e)
    const bf16x8 b0 = *(const bf16x8*)&SH[OFF_W + 2*1280 + c*ST + g*8];
    const bf16x8 b1 = *(const bf16x8*)&SH[OFF_W + 2*1280 + (16 + c)*ST + g*8];
    const float bv0 = sBias[64 + c], bv1 = sBias[64 + 16 + c];
    f32x4 z0 = {bv0, bv0, bv0, bv0}, z1 = {bv1, bv1, bv1, bv1};
    vacc0 = __builtin_amdgcn_mfma_f32_16x16x32_bf16(aV, b0, z0, 0, 0, 0);
    vacc1 = __builtin_amdgcn_mfma_f32_16x16x32_bf16(aV, b1, z1, 0, 0, 0);
  }
  __syncthreads();   // barrier 2: K2/q visible; WQ/WK reads drained

  // ---- V2t -> dead WQ+WK region; per-lane mask words; QK^T fragment reads ----
  {
    const int j0 = wv*16 + g*4;
    const float v0 = (j0+0 < 50) ? vacc0[0] : 0.f;
    const float v1 = (j0+1 < 50) ? vacc0[1] : 0.f;
    const float v2 = (j0+2 < 50) ? vacc0[2] : 0.f;
    const float v3 = (j0+3 < 50) ? vacc0[3] : 0.f;
    *(uint2*)&SH[OFF_V2 + c*SV + j0] = make_uint2(cvt2(v0,v1), cvt2(v2,v3));
    const float u0 = (j0+0 < 50) ? vacc1[0] : 0.f;
    const float u1 = (j0+1 < 50) ? vacc1[1] : 0.f;
    const float u2 = (j0+2 < 50) ? vacc1[2] : 0.f;
    const float u3 = (j0+3 < 50) ? vacc1[3] : 0.f;
    *(uint2*)&SH[OFF_V2 + (16 + c)*SV + j0] = make_uint2(cvt2(u0,u1), cvt2(u2,u3));
  }
  unsigned mm0, mm1;
  {
    const int bp = (myrow < 50) ? 50*myrow : 0;        // direct funnel from sRaw
    const unsigned ra = sRaw[(bp >> 5) + 0];
    const unsigned rb = sRaw[(bp >> 5) + 1];
    const unsigned rc = sRaw[(bp >> 5) + 2];
    const unsigned sh = bp & 31;
    mm0 = (unsigned)((((unsigned long long)rb << 32) | ra) >> sh);
    mm1 = (unsigned)((((unsigned long long)rc << 32) | rb) >> sh);
    if (myrow >= 50) { mm0 = ~0u; mm1 = ~0u; }
  }
  const bf16x8 qb = *(const bf16x8*)&SH[OFF_C + myrow*ST + g*8];
  bf16x8 kf[4];
  #pragma unroll
  for (int Ni = 0; Ni < 4; ++Ni)
    kf[Ni] = *(const bf16x8*)&SH[OFF_A + (Ni*16 + c)*ST + g*8];
  __syncthreads();   // barrier 3: V2t visible

  // ---- head loop: QK^T -> exp -> permlane transpose -> PV, all P in registers ----
  const bf16x8 zf = {0,0,0,0,0,0,0,0};
  unsigned ox0[4], ox1[4];   // ctx bf16 pairs per head (groups duplicated), for epilogue
  #pragma unroll
  for (int h = 0; h < 4; ++h) {
    const bf16x8 vf0 = *(const bf16x8*)&SH[OFF_V2 + (h*8 + (c & 7))*SV + g*8];
    const bf16x8 vf1 = *(const bf16x8*)&SH[OFF_V2 + (h*8 + (c & 7))*SV + 32 + g*8];
    const bf16x8 qh = (g == h) ? qb : zf;    // zero non-head contraction slices
    unsigned pk[8];
    float rs = 0.f;
    #pragma unroll
    for (int Ni = 0; Ni < 4; ++Ni) {
      f32x4 z = {0.f, 0.f, 0.f, 0.f};
      const f32x4 s = __builtin_amdgcn_mfma_f32_16x16x32_bf16(kf[Ni], qh, z, 0, 0, 0);
      const unsigned w = (Ni < 2) ? mm0 : mm1;
      float p[4];
      #pragma unroll
      for (int r = 0; r < 4; ++r) {
        const int key = Ni*16 + g*4 + r;
        const bool keep = (key < 50) && (((w >> (key & 31)) & 1u) == 0u);
        p[r] = keep ? fexp2(s[r]) : 0.f;     // select kills masked/pad/inf/NaN
        rs += p[r];
      }
      pk[Ni*2]   = cvt2(p[0], p[1]);
      pk[Ni*2+1] = cvt2(p[2], p[3]);
    }
    rs += __shfl_xor(rs, 16);
    rs += __shfl_xor(rs, 32);
    const float ri = __builtin_amdgcn_rcpf(rs);
    // B-fragment assembly (target word w @ group g = keys g*8+2w+{0,1}):
    // word0 = aOut(pk0,pk2), word1 = aOut(pk1,pk3), word2 = bOut(pk0,pk2), word3 = bOut(pk1,pk3)
    unsigned w0 = pk[0], w2 = pk[2];  xchF(w0, w2);
    unsigned w1 = pk[1], w3 = pk[3];  xchF(w1, w3);
    unsigned x0 = pk[4], x2 = pk[6];  xchF(x0, x2);
    unsigned x1 = pk[5], x3 = pk[7];  xchF(x1, x3);
    const u32x4 w0v = {w0, w1, w2, w3};
    const u32x4 w1v = {x0, x1, x2, x3};
    const bf16x8 pf0 = __builtin_bit_cast(bf16x8, w0v);
    const bf16x8 pf1 = __builtin_bit_cast(bf16x8, w1v);
    f32x4 cac = {0.f, 0.f, 0.f, 0.f};
    cac = __builtin_amdgcn_mfma_f32_16x16x32_bf16(vf0, pf0, cac, 0, 0, 0);
    cac = __builtin_amdgcn_mfma_f32_16x16x32_bf16(vf1, pf1, cac, 0, 0, 0);
    // lane (c,g) holds ctx dims d' = (g&1)*4 + {0..3} of head h (groups 2,3 duplicate 0,1)
    ox0[h] = cvt2(cac[0]*ri, cac[1]*ri);     // dims (g&1)*4 + {0,1}
    ox1[h] = cvt2(cac[2]*ri, cac[3]*ri);     // dims (g&1)*4 + {2,3}
  }

  // ---- epilogue: ctx A-fragment via permlane tree; out = ctx@WO + bO + Q ----
  {
    float res[2][4];
    #pragma unroll
    for (int Nj = 0; Nj < 2; ++Nj)
      #pragma unroll
      for (int r = 0; r < 4; ++r) {
        const int row = wv*16 + g*4 + r;
        res[Nj][r] = (row < 50) ? Qg[b*1600 + row*32 + Nj*16 + c] : 0.f;
      }
    // inputs per group: ox0[h] = [A_h, B_h, A_h, B_h] (A = dims0-1, B = dims4-5);
    // tree: word0 = [A0,A1,A2,A3] (head g dims(0,1)), word2 = [B0..B3]
    unsigned a0 = ox0[0], a1 = ox0[1], a2 = ox0[2], a3 = ox0[3];
    xchF(a0, a1);          // a0=[A0,A0,A1,A1], a1=[B0,B0,B1,B1]
    xchF(a2, a3);          // a2=[A2,A2,A3,A3], a3=[B2,B2,B3,B3]
    xchF(a0, a2);          // a0=[A0,A1,A2,A3] = word0
    xchF(a1, a3);          // a1=[B0,B1,B2,B3] = word2
    unsigned c0 = ox1[0], c1 = ox1[1], c2 = ox1[2], c3 = ox1[3];
    xchF(c0, c1);          // c0=[C0,C0,C1,C1] (C = dims2-3), c1=[D0,D0,D1,D1]
    xchF(c2, c3);
    xchF(c0, c2);          // c0 = word1
    xchF(c1, c3);          // c1 = word3
    const u32x4 afv = {a0, c0, a1, c1};
    const bf16x8 af = __builtin_bit_cast(bf16x8, afv);
    #pragma unroll
    for (int Nj = 0; Nj < 2; ++Nj) {
      const bf16x8 bbf = *(const bf16x8*)&SH[OFF_W + 3*1280 + (Nj*16 + c)*ST + g*8];
      const float bv = sBias[96 + Nj*16 + c];
      f32x4 o = {bv, bv, bv, bv};
      o = __builtin_amdgcn_mfma_f32_16x16x32_bf16(af, bbf, o, 0, 0, 0);
      #pragma unroll
      for (int r = 0; r < 4; ++r) {
        const int row = wv*16 + g*4 + r;
        if (row < 50)
          outg[b*1600 + row*32 + Nj*16 + c] = o[r] + res[Nj][r];
      }
    }
  }
}

extern "C" void kernel_launch(void* const* d_in, const int* in_sizes, int n_in,
                              void* d_out, int out_size, void* d_ws, size_t ws_size,
                              hipStream_t stream) {
  const float* Q  = (const float*)d_in[0];
  const float* K  = (const float*)d_in[1];
  const float* V  = (const float*)d_in[2];
  const void*  M  = d_in[3];
  const float* WQ = (const float*)d_in[4];
  const float* bQ = (const float*)d_in[5];
  const float* WK = (const float*)d_in[6];
  const float* bK = (const float*)d_in[7];
  const float* WV = (const float*)d_in[8];
  const float* bV = (const float*)d_in[9];
  const float* WO = (const float*)d_in[10];
  const float* bO = (const float*)d_in[11];
  float* out = (float*)d_out;
  (void)d_ws; (void)ws_size; (void)in_sizes; (void)n_in; (void)out_size;

  hipLaunchKernelGGL(mha, dim3(NB), dim3(256), 0, stream,
                     Q, K, V, M, WQ, bQ, WK, bK, WV, bV, WO, bO, out);
}

// Round 13
// 54.619 us; speedup vs baseline: 2.2541x; 1.0337x over previous
//
#include <hip/hip_runtime.h>

// B=4096, S=50, D=32, H=4, HD=8. One block = one batch, 256 threads, wave = 16-row tile.
// Raw tiles and ALL projection intermediates live in registers (A/B fragments share the
// per-lane layout; pass->pass handoff is 2 xchF permlane transposes). LDS holds only
// W^T, K2, V2t (overlay) -> ~16.2 KB -> 8 blocks/CU. 3 barriers.
#define NB 4096
// fold 1/sqrt(8)*log2(e) into q: softmax uses raw v_exp_f32 (=2^x)
constexpr float kQscale = 0.35355339059327378f * 1.4426950408889634f;

constexpr int ST = 40;     // K2 tile stride (shorts)
constexpr int SV = 72;     // V2t stride [d][j]
constexpr int OFF_W  = 0;      // 5120 shorts: W^T bf16 [d][k]: WQ|WK|WV|WO
constexpr int OFF_V2 = 0;      // 2304 shorts: V2t [32][SV] overlays dead WQ+WK after barrier 2
constexpr int OFF_K2 = 5120;   // 2560 shorts: K2 [64][ST]
constexpr int SH_LEN = 7680;   // 15,360 B (+bias 512B + raw 320B) ≈ 16.2 KB

typedef __attribute__((ext_vector_type(8))) short bf16x8;
typedef __attribute__((ext_vector_type(4))) float f32x4;
typedef __attribute__((ext_vector_type(4))) unsigned u32x4;

__device__ __forceinline__ unsigned cvt2(float lo, float hi) {  // 2xf32 -> packed bf16 RNE
  unsigned u;
  asm("v_cvt_pk_bf16_f32 %0, %1, %2" : "=v"(u) : "v"(lo), "v"(hi));
  return u;
}
__device__ __forceinline__ float fexp2(float x) {               // 2^x, 1 inst
  float r;
  asm("v_exp_f32 %0, %1" : "=v"(r) : "v"(x));
  return r;
}
// xchF(a,b): P32(dst=a,src=b); P16(dst=a,src=b).
// Net by 16-lane groups: a = [a0,a2,b0,b2], b = [a1,a3,b1,b3].  (HW-verified r12)
__device__ __forceinline__ void xchF(unsigned& a, unsigned& b) {
  asm volatile("v_permlane32_swap_b32 %0, %1" : "+v"(a), "+v"(b));
  asm volatile("v_permlane16_swap_b32 %0, %1" : "+v"(a), "+v"(b));
}

__global__ __launch_bounds__(256) void mha(
    const float* __restrict__ Qg, const float* __restrict__ Kg,
    const float* __restrict__ Vg, const void* __restrict__ maskg,
    const float* __restrict__ WQg, const float* __restrict__ bQg,
    const float* __restrict__ WKg, const float* __restrict__ bKg,
    const float* __restrict__ WVg, const float* __restrict__ bVg,
    const float* __restrict__ WOg, const float* __restrict__ bOg,
    float* __restrict__ outg)
{
  __shared__ __align__(16) short SH[SH_LEN];
  __shared__ __align__(16) float sBias[128];   // bQ|bK|bV|bO
  __shared__ unsigned sRaw[80];                // ballot-packed mask bits (2500)

  const int t = threadIdx.x;
  const int b = blockIdx.x;
  const int lane = t & 63;
  const int wv = t >> 6;
  const int c = lane & 15, g = lane >> 4;
  const int myrow = wv*16 + c;                 // the [s]-row / q-row this lane owns

  auto mkfrag = [&](float4 x0, float4 x1) -> bf16x8 {
    const u32x4 u = {cvt2(x0.x,x0.y), cvt2(x0.z,x0.w), cvt2(x1.x,x1.y), cvt2(x1.z,x1.w)};
    return __builtin_bit_cast(bf16x8, u);
  };

  // ---- raw K/Q/V rows straight to registers (wave covers a contiguous 2KB/tensor;
  //      pad rows clamp to row 0: finite, killed by downstream guards) ----
  bf16x8 xbK, xbQ, xbV;
  {
    const int ra = b*1600 + ((myrow < 50) ? myrow : 0)*32 + g*8;
    const float4 ka = *(const float4*)&Kg[ra];
    const float4 kb = *(const float4*)&Kg[ra + 4];
    const float4 qa = *(const float4*)&Qg[ra];
    const float4 qc = *(const float4*)&Qg[ra + 4];
    const float4 va = *(const float4*)&Vg[ra];
    const float4 vb = *(const float4*)&Vg[ra + 4];
    xbK = mkfrag(ka, kb); xbQ = mkfrag(qa, qc); xbV = mkfrag(va, vb);
  }

  // ---- mask: speculative byte loads + width detection + ballot pack ----
  const unsigned w64det = ((const unsigned*)maskg)[lane];
  unsigned valB[10];
  #pragma unroll
  for (int cc = 0; cc < 10; ++cc) {
    const int idx = (wv*10 + cc)*64 + lane;
    valB[cc] = (idx < 2500) ? (unsigned)((const unsigned char*)maskg)[b*2500 + idx] : 0u;
  }
  // ---- W^T staging (packed b64 LDS writes) + biases ----
  {
    const int wd = t & 31, wk0 = (t >> 5) * 4;
    #pragma unroll
    for (int m = 0; m < 4; ++m) {
      const float* Wp = (m == 0) ? WQg : (m == 1) ? WKg : (m == 2) ? WVg : WOg;
      const float w0 = Wp[(wk0+0)*32 + wd];
      const float w1 = Wp[(wk0+1)*32 + wd];
      const float w2 = Wp[(wk0+2)*32 + wd];
      const float w3 = Wp[(wk0+3)*32 + wd];
      *(uint2*)&SH[OFF_W + m*1280 + wd*ST + wk0] = make_uint2(cvt2(w0,w1), cvt2(w2,w3));
    }
  }
  if      (t < 32)  sBias[t] = bQg[t];
  else if (t < 64)  sBias[t] = bKg[t-32];
  else if (t < 96)  sBias[t] = bVg[t-64];
  else if (t < 128) sBias[t] = bOg[t-96];
  {
    const bool byteMask = (__ballot(w64det > 1u) != 0ull);  // int32 0/1 words never >1
    #pragma unroll
    for (int cc = 0; cc < 10; ++cc) {
      const int ch = wv*10 + cc;
      const int idx = ch*64 + lane;
      unsigned val;
      if (byteMask) val = valB[cc];
      else          val = (idx < 2500) ? ((const unsigned*)maskg)[b*2500 + idx] : 0u;
      const unsigned long long m = __ballot(val != 0u);
      if (lane == 0) {
        sRaw[ch*2]     = (unsigned)m;
        sRaw[ch*2 + 1] = (unsigned)(m >> 32);
      }
    }
  }
  __syncthreads();   // barrier 1: W^T, biases, sRaw visible

  // ---- per-lane mask words (funnel from sRaw) ----
  unsigned mm0, mm1;
  {
    const int bp = (myrow < 50) ? 50*myrow : 0;
    const unsigned ra = sRaw[(bp >> 5) + 0];
    const unsigned rb = sRaw[(bp >> 5) + 1];
    const unsigned rc = sRaw[(bp >> 5) + 2];
    const unsigned sh = bp & 31;
    mm0 = (unsigned)((((unsigned long long)rb << 32) | ra) >> sh);
    mm1 = (unsigned)((((unsigned long long)rc << 32) | rb) >> sh);
    if (myrow >= 50) { mm0 = ~0u; mm1 = ~0u; }
  }

  // one projection level, fully in registers: Y^T = W^T X^T (+bias),
  // then 2 xchF -> Y row as the next B/A-fragment. (exchange derivation in header)
  auto projR = [&](bf16x8 xb, int wm, int biasOff, float scale) -> bf16x8 {
    const bf16x8 wa0 = *(const bf16x8*)&SH[OFF_W + wm*1280 + c*ST + g*8];
    const bf16x8 wa1 = *(const bf16x8*)&SH[OFF_W + wm*1280 + (16 + c)*ST + g*8];
    const float4 bv0 = *(const float4*)&sBias[biasOff + g*4];
    const float4 bv1 = *(const float4*)&sBias[biasOff + 16 + g*4];
    f32x4 c0 = {bv0.x, bv0.y, bv0.z, bv0.w};
    f32x4 c1 = {bv1.x, bv1.y, bv1.z, bv1.w};
    c0 = __builtin_amdgcn_mfma_f32_16x16x32_bf16(wa0, xb, c0, 0, 0, 0);
    c1 = __builtin_amdgcn_mfma_f32_16x16x32_bf16(wa1, xb, c1, 0, 0, 0);
    unsigned A0 = cvt2(c0[0]*scale, c0[1]*scale), A1 = cvt2(c0[2]*scale, c0[3]*scale);
    unsigned B0 = cvt2(c1[0]*scale, c1[1]*scale), B1 = cvt2(c1[2]*scale, c1[3]*scale);
    xchF(A0, B0); xchF(A1, B1);
    const u32x4 u = {A0, A1, B0, B1};
    return __builtin_bit_cast(bf16x8, u);
  };

  // ---- projections: K,V,Q pass1 (regs) ; pass2 K->LDS, Q->regs, V->regs ----
  const bf16x8 k1f = projR(xbK, 1, 32, 1.f);
  const bf16x8 v1f = projR(xbV, 2, 64, 1.f);
  const bf16x8 q1f = projR(xbQ, 0, 0,  1.f);
  {  // pass2 K -> K2 tile in LDS ([s][d], packed b64 writes)
    #pragma unroll
    for (int Ni = 0; Ni < 2; ++Ni) {
      const bf16x8 wa = *(const bf16x8*)&SH[OFF_W + 1*1280 + (Ni*16 + c)*ST + g*8];
      const float4 bv = *(const float4*)&sBias[32 + Ni*16 + g*4];
      f32x4 acc = {bv.x, bv.y, bv.z, bv.w};
      acc = __builtin_amdgcn_mfma_f32_16x16x32_bf16(wa, k1f, acc, 0, 0, 0);
      *(uint2*)&SH[OFF_K2 + myrow*ST + Ni*16 + g*4] =
          make_uint2(cvt2(acc[0], acc[1]), cvt2(acc[2], acc[3]));
    }
  }
  const bf16x8 qb = projR(q1f, 0, 0, kQscale);   // q fragment (scale incl. log2e)
  f32x4 vacc0, vacc1;                            // V pass2 (normal orientation) in regs
  {
    const bf16x8 wb0 = *(const bf16x8*)&SH[OFF_W + 2*1280 + c*ST + g*8];
    const bf16x8 wb1 = *(const bf16x8*)&SH[OFF_W + 2*1280 + (16 + c)*ST + g*8];
    const float bv0 = sBias[64 + c], bv1 = sBias[64 + 16 + c];
    f32x4 z0 = {bv0, bv0, bv0, bv0}, z1 = {bv1, bv1, bv1, bv1};
    vacc0 = __builtin_amdgcn_mfma_f32_16x16x32_bf16(v1f, wb0, z0, 0, 0, 0);
    vacc1 = __builtin_amdgcn_mfma_f32_16x16x32_bf16(v1f, wb1, z1, 0, 0, 0);
  }
  __syncthreads();   // barrier 2: K2 visible; WQ/WK reads drained

  // ---- V2t -> dead WQ+WK region; K2 A-fragments ----
  {
    const int j0 = wv*16 + g*4;
    const float v0 = (j0+0 < 50) ? vacc0[0] : 0.f;
    const float v1 = (j0+1 < 50) ? vacc0[1] : 0.f;
    const float v2 = (j0+2 < 50) ? vacc0[2] : 0.f;
    const float v3 = (j0+3 < 50) ? vacc0[3] : 0.f;
    *(uint2*)&SH[OFF_V2 + c*SV + j0] = make_uint2(cvt2(v0,v1), cvt2(v2,v3));
    const float u0 = (j0+0 < 50) ? vacc1[0] : 0.f;
    const float u1 = (j0+1 < 50) ? vacc1[1] : 0.f;
    const float u2 = (j0+2 < 50) ? vacc1[2] : 0.f;
    const float u3 = (j0+3 < 50) ? vacc1[3] : 0.f;
    *(uint2*)&SH[OFF_V2 + (16 + c)*SV + j0] = make_uint2(cvt2(u0,u1), cvt2(u2,u3));
  }
  bf16x8 kf[4];
  #pragma unroll
  for (int Ni = 0; Ni < 4; ++Ni)
    kf[Ni] = *(const bf16x8*)&SH[OFF_K2 + (Ni*16 + c)*ST + g*8];
  __syncthreads();   // barrier 3: V2t visible

  // ---- head loop: QK^T -> exp -> xchF transpose -> PV, all P in registers ----
  const bf16x8 zf = {0,0,0,0,0,0,0,0};
  unsigned ox0[4], ox1[4];
  #pragma unroll
  for (int h = 0; h < 4; ++h) {
    const bf16x8 vf0 = *(const bf16x8*)&SH[OFF_V2 + (h*8 + (c & 7))*SV + g*8];
    const bf16x8 vf1 = *(const bf16x8*)&SH[OFF_V2 + (h*8 + (c & 7))*SV + 32 + g*8];
    const bf16x8 qh = (g == h) ? qb : zf;    // zero non-head contraction slices
    unsigned pk[8];
    float rs = 0.f;
    #pragma unroll
    for (int Ni = 0; Ni < 4; ++Ni) {
      f32x4 z = {0.f, 0.f, 0.f, 0.f};
      const f32x4 s = __builtin_amdgcn_mfma_f32_16x16x32_bf16(kf[Ni], qh, z, 0, 0, 0);
      const unsigned w = (Ni < 2) ? mm0 : mm1;
      float p[4];
      #pragma unroll
      for (int r = 0; r < 4; ++r) {
        const int key = Ni*16 + g*4 + r;
        const bool keep = (key < 50) && (((w >> (key & 31)) & 1u) == 0u);
        p[r] = keep ? fexp2(s[r]) : 0.f;     // select kills masked/pad/inf/NaN
        rs += p[r];
      }
      pk[Ni*2]   = cvt2(p[0], p[1]);
      pk[Ni*2+1] = cvt2(p[2], p[3]);
    }
    rs += __shfl_xor(rs, 16);
    rs += __shfl_xor(rs, 32);
    const float ri = __builtin_amdgcn_rcpf(rs);
    unsigned w0 = pk[0], w2 = pk[2];  xchF(w0, w2);
    unsigned w1 = pk[1], w3 = pk[3];  xchF(w1, w3);
    unsigned x0 = pk[4], x2 = pk[6];  xchF(x0, x2);
    unsigned x1 = pk[5], x3 = pk[7];  xchF(x1, x3);
    const u32x4 w0v = {w0, w1, w2, w3};
    const u32x4 w1v = {x0, x1, x2, x3};
    const bf16x8 pf0 = __builtin_bit_cast(bf16x8, w0v);
    const bf16x8 pf1 = __builtin_bit_cast(bf16x8, w1v);
    f32x4 cac = {0.f, 0.f, 0.f, 0.f};
    cac = __builtin_amdgcn_mfma_f32_16x16x32_bf16(vf0, pf0, cac, 0, 0, 0);
    cac = __builtin_amdgcn_mfma_f32_16x16x32_bf16(vf1, pf1, cac, 0, 0, 0);
    ox0[h] = cvt2(cac[0]*ri, cac[1]*ri);
    ox1[h] = cvt2(cac[2]*ri, cac[3]*ri);
  }

  // ---- epilogue: ctx A-fragment via xchF tree; out = ctx@WO + bO + Q ----
  {
    float res[2][4];
    #pragma unroll
    for (int Nj = 0; Nj < 2; ++Nj)
      #pragma unroll
      for (int r = 0; r < 4; ++r) {
        const int row = wv*16 + g*4 + r;
        res[Nj][r] = (row < 50) ? Qg[b*1600 + row*32 + Nj*16 + c] : 0.f;
      }
    unsigned a0 = ox0[0], a1 = ox0[1], a2 = ox0[2], a3 = ox0[3];
    xchF(a0, a1);
    xchF(a2, a3);
    xchF(a0, a2);          // a0 = word0
    xchF(a1, a3);          // a1 = word2
    unsigned c0 = ox1[0], c1 = ox1[1], c2 = ox1[2], c3 = ox1[3];
    xchF(c0, c1);
    xchF(c2, c3);
    xchF(c0, c2);          // c0 = word1
    xchF(c1, c3);          // c1 = word3
    const u32x4 afv = {a0, c0, a1, c1};
    const bf16x8 af = __builtin_bit_cast(bf16x8, afv);
    #pragma unroll
    for (int Nj = 0; Nj < 2; ++Nj) {
      const bf16x8 bbf = *(const bf16x8*)&SH[OFF_W + 3*1280 + (Nj*16 + c)*ST + g*8];
      const float bv = sBias[96 + Nj*16 + c];
      f32x4 o = {bv, bv, bv, bv};
      o = __builtin_amdgcn_mfma_f32_16x16x32_bf16(af, bbf, o, 0, 0, 0);
      #pragma unroll
      for (int r = 0; r < 4; ++r) {
        const int row = wv*16 + g*4 + r;
        if (row < 50)
          outg[b*1600 + row*32 + Nj*16 + c] = o[r] + res[Nj][r];
      }
    }
  }
}

extern "C" void kernel_launch(void* const* d_in, const int* in_sizes, int n_in,
                              void* d_out, int out_size, void* d_ws, size_t ws_size,
                              hipStream_t stream) {
  const float* Q  = (const float*)d_in[0];
  const float* K  = (const float*)d_in[1];
  const float* V  = (const float*)d_in[2];
  const void*  M  = d_in[3];
  const float* WQ = (const float*)d_in[4];
  const float* bQ = (const float*)d_in[5];
  const float* WK = (const float*)d_in[6];
  const float* bK = (const float*)d_in[7];
  const float* WV = (const float*)d_in[8];
  const float* bV = (const float*)d_in[9];
  const float* WO = (const float*)d_in[10];
  const float* bO = (const float*)d_in[11];
  float* out = (float*)d_out;
  (void)d_ws; (void)ws_size; (void)in_sizes; (void)n_in; (void)out_size;

  hipLaunchKernelGGL(mha, dim3(NB), dim3(256), 0, stream,
                     Q, K, V, M, WQ, bQ, WK, bK, WV, bV, WO, bO, out);
}